// Round 17
// baseline (220.018 us; speedup 1.0000x reference)
//
#include <hip/hip_runtime.h>
#include <hip/hip_bf16.h>

#define EMB 256
#define SEQ 21760
#define NB 2
#define NROW (NB * SEQ)   // 43520
#define QB 8              // queries per k_sample block
#define LN_EPS 1e-5f

typedef __hip_bfloat16 bf16;
typedef short bf16x8 __attribute__((ext_vector_type(8)));
typedef float f32x4 __attribute__((ext_vector_type(4)));

__device__ __forceinline__ unsigned short f2bf(float f) {
  __hip_bfloat16 h = __float2bfloat16(f);
  return *reinterpret_cast<unsigned short*>(&h);
}
__device__ __forceinline__ float bf2f(unsigned short u) {
  return __uint_as_float((unsigned int)u << 16);
}
__device__ __forceinline__ float bflo(unsigned int u) { return __uint_as_float(u << 16); }
__device__ __forceinline__ float bfhi(unsigned int u) { return __uint_as_float(u & 0xffff0000u); }

// ---------------- K0: bf16 transpose of W[k][n] -> Wt[n][k] -----------------
__global__ __launch_bounds__(256) void k_trans(const float* __restrict__ src,
                                               unsigned short* __restrict__ dst, int N) {
  const int n = blockIdx.x, k = threadIdx.x;
  dst[n * 256 + k] = f2bf(src[k * N + n]);
}

// ---------------- K1: V = mask ? 0 : (A @ Wt + bias)  -> bf16 HEAD-MAJOR ----
// (byte-identical to round 16 — proven)
__global__ __launch_bounds__(256) void k_value(const float* __restrict__ A,
                                               const unsigned short* __restrict__ Wt,
                                               const float* __restrict__ bias,
                                               const unsigned char* __restrict__ mask,
                                               bf16* __restrict__ V) {
  __shared__ unsigned short As[64 * 256];  // 32KB, XOR-swizzled
  const int tid = threadIdx.x;
  const int lane = tid & 63, w = tid >> 6;
  const int row0 = blockIdx.x * 64;
#pragma unroll
  for (int it = 0; it < 8; ++it) {
    const int cid = it * 256 + tid;
    const int row = cid >> 5, c = cid & 31;
    const float4* p = (const float4*)(A + (size_t)(row0 + row) * 256 + c * 8);
    const float4 a0 = p[0], a1 = p[1];
    union { unsigned short u[8]; uint4 q; } pk;
    pk.u[0] = f2bf(a0.x); pk.u[1] = f2bf(a0.y); pk.u[2] = f2bf(a0.z); pk.u[3] = f2bf(a0.w);
    pk.u[4] = f2bf(a1.x); pk.u[5] = f2bf(a1.y); pk.u[6] = f2bf(a1.z); pk.u[7] = f2bf(a1.w);
    *(uint4*)((char*)As + row * 512 + ((c * 16) ^ ((row & 7) << 4))) = pk.q;
  }
  __syncthreads();
  const int lg16 = lane >> 4, l16 = lane & 15;
  f32x4 acc[4][4] = {};
#pragma unroll
  for (int kk = 0; kk < 8; ++kk) {
    bf16x8 af[4], bh[4];
#pragma unroll
    for (int mf = 0; mf < 4; ++mf) {
      const int row = mf * 16 + l16;
      af[mf] = *(const bf16x8*)((const char*)As + row * 512 +
                                ((kk * 64 + lg16 * 16) ^ ((row & 7) << 4)));
    }
#pragma unroll
    for (int nf = 0; nf < 4; ++nf) {
      const int col = w * 64 + nf * 16 + l16;
      bh[nf] = *(const bf16x8*)(Wt + (size_t)col * 256 + kk * 32 + lg16 * 8);
    }
#pragma unroll
    for (int mf = 0; mf < 4; ++mf)
#pragma unroll
      for (int nf = 0; nf < 4; ++nf)
        acc[mf][nf] = __builtin_amdgcn_mfma_f32_16x16x32_bf16(af[mf], bh[nf], acc[mf][nf], 0, 0, 0);
  }
#pragma unroll
  for (int mf = 0; mf < 4; ++mf) {
    const int rbase = mf * 16 + lg16 * 4;
    const uchar4 mk = *(const uchar4*)(mask + row0 + rbase);
#pragma unroll
    for (int nf = 0; nf < 4; ++nf) {
      const int col = w * 64 + nf * 16 + l16;
      const int hh = col >> 5, ch = col & 31;   // head-major decomposition
      const float bb = bias[col];
#pragma unroll
      for (int r = 0; r < 4; ++r) {
        const unsigned char m = (r == 0) ? mk.x : (r == 1) ? mk.y : (r == 2) ? mk.z : mk.w;
        const float v = m ? 0.f : (acc[mf][nf][r] + bb);
        V[(size_t)hh * (NROW * 32) + (size_t)(row0 + rbase + r) * 32 + ch] =
            __float2bfloat16(v);
      }
    }
  }
}

// ---------------- K2: q = qf+qp; [off|lg] = q @ Wcat -> bf16 ----------------
// (byte-identical to round 11 — proven)
__global__ __launch_bounds__(256) void k_offattn(const float* __restrict__ qf,
                                                 const float* __restrict__ qp,
                                                 const unsigned short* __restrict__ Wt,
                                                 const float* __restrict__ boff,
                                                 const float* __restrict__ battn,
                                                 bf16* __restrict__ off,
                                                 bf16* __restrict__ lg) {
  __shared__ unsigned short As[64 * 256];
  const int tid = threadIdx.x;
  const int lane = tid & 63, w = tid >> 6;
  const int row0 = blockIdx.x * 64;
#pragma unroll
  for (int it = 0; it < 8; ++it) {
    const int cid = it * 256 + tid;
    const int row = cid >> 5, c = cid & 31;
    const float4* pf = (const float4*)(qf + (size_t)(row0 + row) * 256 + c * 8);
    const float4* pp = (const float4*)(qp + (size_t)(row0 + row) * 256 + c * 8);
    const float4 a0 = pf[0], a1 = pf[1], b0 = pp[0], b1 = pp[1];
    union { unsigned short u[8]; uint4 q; } pk;
    pk.u[0] = f2bf(a0.x + b0.x); pk.u[1] = f2bf(a0.y + b0.y);
    pk.u[2] = f2bf(a0.z + b0.z); pk.u[3] = f2bf(a0.w + b0.w);
    pk.u[4] = f2bf(a1.x + b1.x); pk.u[5] = f2bf(a1.y + b1.y);
    pk.u[6] = f2bf(a1.z + b1.z); pk.u[7] = f2bf(a1.w + b1.w);
    *(uint4*)((char*)As + row * 512 + ((c * 16) ^ ((row & 7) << 4))) = pk.q;
  }
  __syncthreads();
  const int lg16 = lane >> 4, l16 = lane & 15;
  f32x4 acc[4][6] = {};
#pragma unroll
  for (int kk = 0; kk < 8; ++kk) {
    bf16x8 af[4], bh[6];
#pragma unroll
    for (int mf = 0; mf < 4; ++mf) {
      const int row = mf * 16 + l16;
      af[mf] = *(const bf16x8*)((const char*)As + row * 512 +
                                ((kk * 64 + lg16 * 16) ^ ((row & 7) << 4)));
    }
#pragma unroll
    for (int nf = 0; nf < 6; ++nf) {
      const int col = w * 96 + nf * 16 + l16;
      bh[nf] = *(const bf16x8*)(Wt + (size_t)col * 256 + kk * 32 + lg16 * 8);
    }
#pragma unroll
    for (int mf = 0; mf < 4; ++mf)
#pragma unroll
      for (int nf = 0; nf < 6; ++nf)
        acc[mf][nf] = __builtin_amdgcn_mfma_f32_16x16x32_bf16(af[mf], bh[nf], acc[mf][nf], 0, 0, 0);
  }
#pragma unroll
  for (int mf = 0; mf < 4; ++mf) {
    const int rbase = row0 + mf * 16 + lg16 * 4;
#pragma unroll
    for (int nf = 0; nf < 6; ++nf) {
      const int col = w * 96 + nf * 16 + l16;
      if (col < 256) {
        const float bb = boff[col];
#pragma unroll
        for (int r = 0; r < 4; ++r)
          off[(size_t)(rbase + r) * 256 + col] = __float2bfloat16(acc[mf][nf][r] + bb);
      } else {
        const float bb = battn[col - 256];
#pragma unroll
        for (int r = 0; r < 4; ++r)
          lg[(size_t)(rbase + r) * 128 + (col - 256)] = __float2bfloat16(acc[mf][nf][r] + bb);
      }
    }
  }
}

// ---------------- K3: softmax + bilinear gather + attn-weighted sum ---------
// Phase 2 is SOFTWARE-PIPELINED: sample i+1's LDS reads + 4 corner loads are
// issued before accumulating sample i (register rotation, ~4-8 loads in
// flight/thread). Everything else identical to round 16.
__global__ __launch_bounds__(256) void k_sample(const bf16* __restrict__ V,
                                                const bf16* off,
                                                const bf16* __restrict__ lg,
                                                const float* __restrict__ qpts,
                                                const float* __restrict__ vratio,
                                                unsigned short* samp) {
  __shared__ uint2 sIdx[QB * 16 * 9];  // [q][i][h(pad 9)] 4x u16 token idx
  __shared__ uint2 sW[QB * 16 * 9];    // 4x bf16 premultiplied weights
  __shared__ float sMax[QB * 8], sInv[QB * 8];
  const int t = threadIdx.x;
  const int row0 = blockIdx.x * QB;

  if (t < QB * 8) {
    const int q = t >> 3, h = t & 7;
    const int row = row0 + q;
    const uint4* lp = (const uint4*)(lg + (size_t)row * 128 + h * 16);
    uint4 u0 = lp[0], u1 = lp[1];
    float v[16];
    v[0] = bflo(u0.x); v[1] = bfhi(u0.x); v[2] = bflo(u0.y); v[3] = bfhi(u0.y);
    v[4] = bflo(u0.z); v[5] = bfhi(u0.z); v[6] = bflo(u0.w); v[7] = bfhi(u0.w);
    v[8] = bflo(u1.x); v[9] = bfhi(u1.x); v[10] = bflo(u1.y); v[11] = bfhi(u1.y);
    v[12] = bflo(u1.z); v[13] = bfhi(u1.z); v[14] = bflo(u1.w); v[15] = bfhi(u1.w);
    float m = v[0];
#pragma unroll
    for (int i = 1; i < 16; ++i) m = fmaxf(m, v[i]);
    float s = 0.f;
#pragma unroll
    for (int i = 0; i < 16; ++i) s += __expf(v[i] - m);
    sMax[t] = m;
    sInv[t] = 1.f / s;
  }
  __syncthreads();

  const int Wl_[4] = {128, 64, 32, 16};
  const int st_[4] = {0, 16384, 20480, 21504};
#pragma unroll
  for (int tt = 0; tt < 4; ++tt) {
    const int sid = t + tt * 256;
    const int q = sid >> 7, s = sid & 127;
    const int h = s >> 4, i = s & 15, l = i >> 2;
    const int row = row0 + q;
    const int b = row >= SEQ;  // NB == 2
    const unsigned int u = *(const unsigned int*)(off + (size_t)row * 256 + s * 2);
    const float ox = bflo(u), oy = bfhi(u);
    const float lgv = bf2f(*(const unsigned short*)(lg + (size_t)row * 128 + s));
    const float e = __expf(lgv - sMax[q * 8 + h]) * sInv[q * 8 + h];
    const float px = qpts[(size_t)row * 2], py = qpts[(size_t)row * 2 + 1];
    const float vrx = vratio[b * 8 + l * 2], vry = vratio[b * 8 + l * 2 + 1];
    const int Wl = Wl_[l];
    const float fW = (float)Wl;
    const float x = fmaf(px * vrx, fW, ox) - 0.5f;
    const float y = fmaf(py * vry, fW, oy) - 0.5f;
    const float fx = floorf(x), fy = floorf(y);
    const float wx = x - fx, wy = y - fy;
    const int x0 = (int)fx, y0 = (int)fy;
    const int x1 = x0 + 1, y1 = y0 + 1;
    const int xc0 = min(max(x0, 0), Wl - 1), xc1 = min(max(x1, 0), Wl - 1);
    const int yc0 = min(max(y0, 0), Wl - 1), yc1 = min(max(y1, 0), Wl - 1);
    const float ox0 = (x0 >= 0 && x0 < Wl) ? e : 0.f;   // fold attn weight in
    const float ox1 = (x1 >= 0 && x1 < Wl) ? e : 0.f;
    const float oy0 = (y0 >= 0 && y0 < Wl) ? 1.f : 0.f;
    const float oy1 = (y1 >= 0 && y1 < Wl) ? 1.f : 0.f;
    const int base = b * SEQ + st_[l];   // max token idx 43519 < 65536 -> u16 ok
    const int r0 = base + yc0 * Wl, r1 = base + yc1 * Wl;
    uint2 I, Wp;
    I.x = (unsigned int)(r0 + xc0) | ((unsigned int)(r0 + xc1) << 16);
    I.y = (unsigned int)(r1 + xc0) | ((unsigned int)(r1 + xc1) << 16);
    Wp.x = (unsigned int)f2bf((1.f - wx) * (1.f - wy) * ox0 * oy0) |
           ((unsigned int)f2bf(wx * (1.f - wy) * ox1 * oy0) << 16);
    Wp.y = (unsigned int)f2bf((1.f - wx) * wy * ox0 * oy1) |
           ((unsigned int)f2bf(wx * wy * ox1 * oy1) << 16);
    sIdx[(q * 16 + i) * 9 + h] = I;
    sW[(q * 16 + i) * 9 + h] = Wp;
  }
  __syncthreads();  // all off/lg reads for this block's rows complete here

  const int q = t >> 5, sub = t & 31;
  const int h = sub >> 2, dg = sub & 3;
  const int row = row0 + q;
  const bf16* vb = V + (size_t)h * (NROW * 32) + dg * 8;  // head-major base
  const int sb = (q * 16) * 9 + h;
  float a0 = 0.f, a1 = 0.f, a2 = 0.f, a3 = 0.f;
  float a4 = 0.f, a5 = 0.f, a6 = 0.f, a7 = 0.f;

  // prologue: sample 0's metadata + corner loads
  uint2 I = sIdx[sb], Wp = sW[sb];
  uint4 A_ = *(const uint4*)(vb + (size_t)(I.x & 0xffff) * 32);
  uint4 B_ = *(const uint4*)(vb + (size_t)(I.x >> 16) * 32);
  uint4 C_ = *(const uint4*)(vb + (size_t)(I.y & 0xffff) * 32);
  uint4 D_ = *(const uint4*)(vb + (size_t)(I.y >> 16) * 32);

#pragma unroll
  for (int i = 0; i < 16; ++i) {
    const float w0 = bflo(Wp.x), w1 = bfhi(Wp.x);
    const float w2 = bflo(Wp.y), w3 = bfhi(Wp.y);
    uint4 An = A_, Bn = B_, Cn = C_, Dn = D_;
    uint2 In = I, Wn = Wp;
    if (i < 15) {  // issue next sample's loads BEFORE consuming current
      In = sIdx[sb + (i + 1) * 9];
      Wn = sW[sb + (i + 1) * 9];
      An = *(const uint4*)(vb + (size_t)(In.x & 0xffff) * 32);
      Bn = *(const uint4*)(vb + (size_t)(In.x >> 16) * 32);
      Cn = *(const uint4*)(vb + (size_t)(In.y & 0xffff) * 32);
      Dn = *(const uint4*)(vb + (size_t)(In.y >> 16) * 32);
    }
    a0 = fmaf(w0, bflo(A_.x), a0); a1 = fmaf(w0, bfhi(A_.x), a1);
    a2 = fmaf(w0, bflo(A_.y), a2); a3 = fmaf(w0, bfhi(A_.y), a3);
    a4 = fmaf(w0, bflo(A_.z), a4); a5 = fmaf(w0, bfhi(A_.z), a5);
    a6 = fmaf(w0, bflo(A_.w), a6); a7 = fmaf(w0, bfhi(A_.w), a7);
    a0 = fmaf(w1, bflo(B_.x), a0); a1 = fmaf(w1, bfhi(B_.x), a1);
    a2 = fmaf(w1, bflo(B_.y), a2); a3 = fmaf(w1, bfhi(B_.y), a3);
    a4 = fmaf(w1, bflo(B_.z), a4); a5 = fmaf(w1, bfhi(B_.z), a5);
    a6 = fmaf(w1, bflo(B_.w), a6); a7 = fmaf(w1, bfhi(B_.w), a7);
    a0 = fmaf(w2, bflo(C_.x), a0); a1 = fmaf(w2, bfhi(C_.x), a1);
    a2 = fmaf(w2, bflo(C_.y), a2); a3 = fmaf(w2, bfhi(C_.y), a3);
    a4 = fmaf(w2, bflo(C_.z), a4); a5 = fmaf(w2, bfhi(C_.z), a5);
    a6 = fmaf(w2, bflo(C_.w), a6); a7 = fmaf(w2, bfhi(C_.w), a7);
    a0 = fmaf(w3, bflo(D_.x), a0); a1 = fmaf(w3, bfhi(D_.x), a1);
    a2 = fmaf(w3, bflo(D_.y), a2); a3 = fmaf(w3, bfhi(D_.y), a3);
    a4 = fmaf(w3, bflo(D_.z), a4); a5 = fmaf(w3, bfhi(D_.z), a5);
    a6 = fmaf(w3, bflo(D_.w), a6); a7 = fmaf(w3, bfhi(D_.w), a7);
    A_ = An; B_ = Bn; C_ = Cn; D_ = Dn; I = In; Wp = Wn;
  }
  uint4 pk;
  pk.x = (unsigned int)f2bf(a0) | ((unsigned int)f2bf(a1) << 16);
  pk.y = (unsigned int)f2bf(a2) | ((unsigned int)f2bf(a3) << 16);
  pk.z = (unsigned int)f2bf(a4) | ((unsigned int)f2bf(a5) << 16);
  pk.w = (unsigned int)f2bf(a6) | ((unsigned int)f2bf(a7) << 16);
  *(uint4*)((char*)samp + (size_t)row * 512 + (h * 32 + dg * 8) * 2) = pk;
}

// ---------------- K4: upd = samp @ WoutT + bout -> bf16 ---------------------
// (byte-identical to round 15 — proven)
__global__ __launch_bounds__(256) void k_upd(const unsigned short* __restrict__ A,
                                             const unsigned short* __restrict__ Wt,
                                             const float* __restrict__ bias,
                                             bf16* __restrict__ U) {
  __shared__ unsigned short As[64 * 256];  // 32KB, XOR-swizzled
  const int tid = threadIdx.x;
  const int lane = tid & 63, w = tid >> 6;
  const int row0 = blockIdx.x * 64;
#pragma unroll
  for (int it = 0; it < 8; ++it) {
    const int cid = it * 256 + tid;
    const int row = cid >> 5, c = cid & 31;
    const uint4 q = *(const uint4*)(A + (size_t)(row0 + row) * 256 + c * 8);
    *(uint4*)((char*)As + row * 512 + ((c * 16) ^ ((row & 7) << 4))) = q;
  }
  __syncthreads();
  const int lg16 = lane >> 4, l16 = lane & 15;
  f32x4 acc[4][4] = {};
#pragma unroll
  for (int kk = 0; kk < 8; ++kk) {
    bf16x8 af[4], bh[4];
#pragma unroll
    for (int mf = 0; mf < 4; ++mf) {
      const int row = mf * 16 + l16;
      af[mf] = *(const bf16x8*)((const char*)As + row * 512 +
                                ((kk * 64 + lg16 * 16) ^ ((row & 7) << 4)));
    }
#pragma unroll
    for (int nf = 0; nf < 4; ++nf) {
      const int col = w * 64 + nf * 16 + l16;
      bh[nf] = *(const bf16x8*)(Wt + (size_t)col * 256 + kk * 32 + lg16 * 8);
    }
#pragma unroll
    for (int mf = 0; mf < 4; ++mf)
#pragma unroll
      for (int nf = 0; nf < 4; ++nf)
        acc[mf][nf] = __builtin_amdgcn_mfma_f32_16x16x32_bf16(af[mf], bh[nf], acc[mf][nf], 0, 0, 0);
  }
#pragma unroll
  for (int mf = 0; mf < 4; ++mf) {
    const int rbase = row0 + mf * 16 + lg16 * 4;
#pragma unroll
    for (int nf = 0; nf < 4; ++nf) {
      const int col = w * 64 + nf * 16 + l16;
      const float bb = bias[col];
#pragma unroll
      for (int r = 0; r < 4; ++r)
        U[(size_t)(rbase + r) * 256 + col] = __float2bfloat16(acc[mf][nf][r] + bb);
    }
  }
}

// ---------------- K5: y = LN(qf + upd) — SOLE writer of d_out ---------------
__global__ __launch_bounds__(256) void k_ln(const unsigned short* __restrict__ upd,
                                            const float* __restrict__ qf,
                                            const float* __restrict__ gamma,
                                            const float* __restrict__ beta,
                                            float* __restrict__ y) {
  const int w = threadIdx.x >> 6, lane = threadIdx.x & 63;
  const int row = blockIdx.x * 4 + w;
  const int c = lane * 4;
  const ushort4 u = *(const ushort4*)(upd + (size_t)row * 256 + c);
  const float4 qv = *(const float4*)(qf + (size_t)row * 256 + c);
  const float x0 = qv.x + bf2f(u.x);
  const float x1 = qv.y + bf2f(u.y);
  const float x2 = qv.z + bf2f(u.z);
  const float x3 = qv.w + bf2f(u.w);
  float s1 = x0 + x1 + x2 + x3;
  float s2 = x0 * x0 + x1 * x1 + x2 * x2 + x3 * x3;
#pragma unroll
  for (int o = 32; o >= 1; o >>= 1) {
    s1 += __shfl_xor(s1, o);
    s2 += __shfl_xor(s2, o);
  }
  const float mu = s1 * (1.f / 256.f);
  const float var = s2 * (1.f / 256.f) - mu * mu;
  const float rsig = rsqrtf(var + LN_EPS);
  const float4 g = *(const float4*)(gamma + c);
  const float4 bt = *(const float4*)(beta + c);
  float4 o;
  o.x = (x0 - mu) * rsig * g.x + bt.x;
  o.y = (x1 - mu) * rsig * g.y + bt.y;
  o.z = (x2 - mu) * rsig * g.z + bt.z;
  o.w = (x3 - mu) * rsig * g.w + bt.w;
  *(float4*)(y + (size_t)row * 256 + c) = o;
}

extern "C" void kernel_launch(void* const* d_in, const int* in_sizes, int n_in,
                              void* d_out, int out_size, void* d_ws, size_t ws_size,
                              hipStream_t stream) {
  const float* img_feat = (const float*)d_in[0];
  const unsigned char* img_mask = (const unsigned char*)d_in[2];
  const float* vratio = (const float*)d_in[3];
  const float* qf = (const float*)d_in[4];
  const float* qp = (const float*)d_in[5];
  const float* qpts = (const float*)d_in[6];
  const float* Wv = (const float*)d_in[7];
  const float* bv = (const float*)d_in[8];
  const float* Woff = (const float*)d_in[9];
  const float* boff = (const float*)d_in[10];
  const float* Wattn = (const float*)d_in[11];
  const float* battn = (const float*)d_in[12];
  const float* Wout = (const float*)d_in[13];
  const float* bout = (const float*)d_in[14];
  const float* gamma = (const float*)d_in[15];
  const float* beta = (const float*)d_in[16];

  char* ws = (char*)d_ws;
  bf16* V = (bf16*)ws;                                   // 22.3 MB (head-major; reused as upd)
  bf16* off = (bf16*)(ws + (size_t)NROW * 256 * 2);      // 22.3 MB (reused as samp)
  bf16* lg = (bf16*)(ws + (size_t)NROW * 256 * 4);       // 11.1 MB
  unsigned short* wbase =
      (unsigned short*)(ws + (size_t)NROW * 256 * 4 + (size_t)NROW * 128 * 2);
  unsigned short* WvT = wbase;              // 65536 shorts
  unsigned short* WcatT = WvT + 65536;      // 98304 shorts
  unsigned short* WoutT = WcatT + 98304;    // 65536 shorts -> ends 56.16MB (< proven 56.36MB)

  dim3 blk(256);
  k_trans<<<256, blk, 0, stream>>>(Wv, WvT, 256);
  k_trans<<<256, blk, 0, stream>>>(Woff, WcatT, 256);
  k_trans<<<128, blk, 0, stream>>>(Wattn, WcatT + 256 * 256, 128);
  k_trans<<<256, blk, 0, stream>>>(Wout, WoutT, 256);
  k_value<<<NROW / 64, blk, 0, stream>>>(img_feat, WvT, bv, img_mask, V);
  k_offattn<<<NROW / 64, blk, 0, stream>>>(qf, qp, WcatT, boff, battn, off, lg);
  k_sample<<<NROW / QB, blk, 0, stream>>>(V, off, lg, qpts, vratio,
                                          (unsigned short*)off /* samp alias */);
  k_upd<<<NROW / 64, blk, 0, stream>>>((const unsigned short*)off /* samp */, WoutT,
                                       bout, V /* = upd, dead */);
  k_ln<<<NROW / 4, blk, 0, stream>>>((const unsigned short*)V, qf, gamma, beta,
                                     (float*)d_out);
}

// Round 18
// 217.341 us; speedup vs baseline: 1.0123x; 1.0123x over previous
//
#include <hip/hip_runtime.h>
#include <hip/hip_bf16.h>

#define EMB 256
#define SEQ 21760
#define NB 2
#define NROW (NB * SEQ)   // 43520
#define QB 8              // queries per k_sample block
#define LN_EPS 1e-5f

typedef __hip_bfloat16 bf16;
typedef short bf16x8 __attribute__((ext_vector_type(8)));
typedef float f32x4 __attribute__((ext_vector_type(4)));

__device__ __forceinline__ unsigned short f2bf(float f) {
  __hip_bfloat16 h = __float2bfloat16(f);
  return *reinterpret_cast<unsigned short*>(&h);
}
__device__ __forceinline__ float bf2f(unsigned short u) {
  return __uint_as_float((unsigned int)u << 16);
}
__device__ __forceinline__ float bflo(unsigned int u) { return __uint_as_float(u << 16); }
__device__ __forceinline__ float bfhi(unsigned int u) { return __uint_as_float(u & 0xffff0000u); }

// ---------------- K0: bf16 transpose of W[k][n] -> Wt[n][k] -----------------
__global__ __launch_bounds__(256) void k_trans(const float* __restrict__ src,
                                               unsigned short* __restrict__ dst, int N) {
  const int n = blockIdx.x, k = threadIdx.x;
  dst[n * 256 + k] = f2bf(src[k * N + n]);
}

// ---------------- K1: V = mask ? 0 : (A @ Wt + bias)  -> bf16 HEAD-MAJOR ----
// (byte-identical to round 16 — proven)
__global__ __launch_bounds__(256) void k_value(const float* __restrict__ A,
                                               const unsigned short* __restrict__ Wt,
                                               const float* __restrict__ bias,
                                               const unsigned char* __restrict__ mask,
                                               bf16* __restrict__ V) {
  __shared__ unsigned short As[64 * 256];  // 32KB, XOR-swizzled
  const int tid = threadIdx.x;
  const int lane = tid & 63, w = tid >> 6;
  const int row0 = blockIdx.x * 64;
#pragma unroll
  for (int it = 0; it < 8; ++it) {
    const int cid = it * 256 + tid;
    const int row = cid >> 5, c = cid & 31;
    const float4* p = (const float4*)(A + (size_t)(row0 + row) * 256 + c * 8);
    const float4 a0 = p[0], a1 = p[1];
    union { unsigned short u[8]; uint4 q; } pk;
    pk.u[0] = f2bf(a0.x); pk.u[1] = f2bf(a0.y); pk.u[2] = f2bf(a0.z); pk.u[3] = f2bf(a0.w);
    pk.u[4] = f2bf(a1.x); pk.u[5] = f2bf(a1.y); pk.u[6] = f2bf(a1.z); pk.u[7] = f2bf(a1.w);
    *(uint4*)((char*)As + row * 512 + ((c * 16) ^ ((row & 7) << 4))) = pk.q;
  }
  __syncthreads();
  const int lg16 = lane >> 4, l16 = lane & 15;
  f32x4 acc[4][4] = {};
#pragma unroll
  for (int kk = 0; kk < 8; ++kk) {
    bf16x8 af[4], bh[4];
#pragma unroll
    for (int mf = 0; mf < 4; ++mf) {
      const int row = mf * 16 + l16;
      af[mf] = *(const bf16x8*)((const char*)As + row * 512 +
                                ((kk * 64 + lg16 * 16) ^ ((row & 7) << 4)));
    }
#pragma unroll
    for (int nf = 0; nf < 4; ++nf) {
      const int col = w * 64 + nf * 16 + l16;
      bh[nf] = *(const bf16x8*)(Wt + (size_t)col * 256 + kk * 32 + lg16 * 8);
    }
#pragma unroll
    for (int mf = 0; mf < 4; ++mf)
#pragma unroll
      for (int nf = 0; nf < 4; ++nf)
        acc[mf][nf] = __builtin_amdgcn_mfma_f32_16x16x32_bf16(af[mf], bh[nf], acc[mf][nf], 0, 0, 0);
  }
#pragma unroll
  for (int mf = 0; mf < 4; ++mf) {
    const int rbase = mf * 16 + lg16 * 4;
    const uchar4 mk = *(const uchar4*)(mask + row0 + rbase);
#pragma unroll
    for (int nf = 0; nf < 4; ++nf) {
      const int col = w * 64 + nf * 16 + l16;
      const int hh = col >> 5, ch = col & 31;   // head-major decomposition
      const float bb = bias[col];
#pragma unroll
      for (int r = 0; r < 4; ++r) {
        const unsigned char m = (r == 0) ? mk.x : (r == 1) ? mk.y : (r == 2) ? mk.z : mk.w;
        const float v = m ? 0.f : (acc[mf][nf][r] + bb);
        V[(size_t)hh * (NROW * 32) + (size_t)(row0 + rbase + r) * 32 + ch] =
            __float2bfloat16(v);
      }
    }
  }
}

// ---------------- K2: q = qf+qp; [off|lg] = q @ Wcat -> bf16 ----------------
// (byte-identical to round 11 — proven)
__global__ __launch_bounds__(256) void k_offattn(const float* __restrict__ qf,
                                                 const float* __restrict__ qp,
                                                 const unsigned short* __restrict__ Wt,
                                                 const float* __restrict__ boff,
                                                 const float* __restrict__ battn,
                                                 bf16* __restrict__ off,
                                                 bf16* __restrict__ lg) {
  __shared__ unsigned short As[64 * 256];
  const int tid = threadIdx.x;
  const int lane = tid & 63, w = tid >> 6;
  const int row0 = blockIdx.x * 64;
#pragma unroll
  for (int it = 0; it < 8; ++it) {
    const int cid = it * 256 + tid;
    const int row = cid >> 5, c = cid & 31;
    const float4* pf = (const float4*)(qf + (size_t)(row0 + row) * 256 + c * 8);
    const float4* pp = (const float4*)(qp + (size_t)(row0 + row) * 256 + c * 8);
    const float4 a0 = pf[0], a1 = pf[1], b0 = pp[0], b1 = pp[1];
    union { unsigned short u[8]; uint4 q; } pk;
    pk.u[0] = f2bf(a0.x + b0.x); pk.u[1] = f2bf(a0.y + b0.y);
    pk.u[2] = f2bf(a0.z + b0.z); pk.u[3] = f2bf(a0.w + b0.w);
    pk.u[4] = f2bf(a1.x + b1.x); pk.u[5] = f2bf(a1.y + b1.y);
    pk.u[6] = f2bf(a1.z + b1.z); pk.u[7] = f2bf(a1.w + b1.w);
    *(uint4*)((char*)As + row * 512 + ((c * 16) ^ ((row & 7) << 4))) = pk.q;
  }
  __syncthreads();
  const int lg16 = lane >> 4, l16 = lane & 15;
  f32x4 acc[4][6] = {};
#pragma unroll
  for (int kk = 0; kk < 8; ++kk) {
    bf16x8 af[4], bh[6];
#pragma unroll
    for (int mf = 0; mf < 4; ++mf) {
      const int row = mf * 16 + l16;
      af[mf] = *(const bf16x8*)((const char*)As + row * 512 +
                                ((kk * 64 + lg16 * 16) ^ ((row & 7) << 4)));
    }
#pragma unroll
    for (int nf = 0; nf < 6; ++nf) {
      const int col = w * 96 + nf * 16 + l16;
      bh[nf] = *(const bf16x8*)(Wt + (size_t)col * 256 + kk * 32 + lg16 * 8);
    }
#pragma unroll
    for (int mf = 0; mf < 4; ++mf)
#pragma unroll
      for (int nf = 0; nf < 6; ++nf)
        acc[mf][nf] = __builtin_amdgcn_mfma_f32_16x16x32_bf16(af[mf], bh[nf], acc[mf][nf], 0, 0, 0);
  }
#pragma unroll
  for (int mf = 0; mf < 4; ++mf) {
    const int rbase = row0 + mf * 16 + lg16 * 4;
#pragma unroll
    for (int nf = 0; nf < 6; ++nf) {
      const int col = w * 96 + nf * 16 + l16;
      if (col < 256) {
        const float bb = boff[col];
#pragma unroll
        for (int r = 0; r < 4; ++r)
          off[(size_t)(rbase + r) * 256 + col] = __float2bfloat16(acc[mf][nf][r] + bb);
      } else {
        const float bb = battn[col - 256];
#pragma unroll
        for (int r = 0; r < 4; ++r)
          lg[(size_t)(rbase + r) * 128 + (col - 256)] = __float2bfloat16(acc[mf][nf][r] + bb);
      }
    }
  }
}

// ---------------- K3: softmax + bilinear gather + attn-weighted sum ---------
// Phase 2 is SOFTWARE-PIPELINED: sample i+1's LDS reads + 4 corner loads are
// issued before accumulating sample i (register rotation, ~4-8 loads in
// flight/thread). Everything else identical to round 16.
__global__ __launch_bounds__(256) void k_sample(const bf16* __restrict__ V,
                                                const bf16* off,
                                                const bf16* __restrict__ lg,
                                                const float* __restrict__ qpts,
                                                const float* __restrict__ vratio,
                                                unsigned short* samp) {
  __shared__ uint2 sIdx[QB * 16 * 9];  // [q][i][h(pad 9)] 4x u16 token idx
  __shared__ uint2 sW[QB * 16 * 9];    // 4x bf16 premultiplied weights
  __shared__ float sMax[QB * 8], sInv[QB * 8];
  const int t = threadIdx.x;
  const int row0 = blockIdx.x * QB;

  if (t < QB * 8) {
    const int q = t >> 3, h = t & 7;
    const int row = row0 + q;
    const uint4* lp = (const uint4*)(lg + (size_t)row * 128 + h * 16);
    uint4 u0 = lp[0], u1 = lp[1];
    float v[16];
    v[0] = bflo(u0.x); v[1] = bfhi(u0.x); v[2] = bflo(u0.y); v[3] = bfhi(u0.y);
    v[4] = bflo(u0.z); v[5] = bfhi(u0.z); v[6] = bflo(u0.w); v[7] = bfhi(u0.w);
    v[8] = bflo(u1.x); v[9] = bfhi(u1.x); v[10] = bflo(u1.y); v[11] = bfhi(u1.y);
    v[12] = bflo(u1.z); v[13] = bfhi(u1.z); v[14] = bflo(u1.w); v[15] = bfhi(u1.w);
    float m = v[0];
#pragma unroll
    for (int i = 1; i < 16; ++i) m = fmaxf(m, v[i]);
    float s = 0.f;
#pragma unroll
    for (int i = 0; i < 16; ++i) s += __expf(v[i] - m);
    sMax[t] = m;
    sInv[t] = 1.f / s;
  }
  __syncthreads();

  const int Wl_[4] = {128, 64, 32, 16};
  const int st_[4] = {0, 16384, 20480, 21504};
#pragma unroll
  for (int tt = 0; tt < 4; ++tt) {
    const int sid = t + tt * 256;
    const int q = sid >> 7, s = sid & 127;
    const int h = s >> 4, i = s & 15, l = i >> 2;
    const int row = row0 + q;
    const int b = row >= SEQ;  // NB == 2
    const unsigned int u = *(const unsigned int*)(off + (size_t)row * 256 + s * 2);
    const float ox = bflo(u), oy = bfhi(u);
    const float lgv = bf2f(*(const unsigned short*)(lg + (size_t)row * 128 + s));
    const float e = __expf(lgv - sMax[q * 8 + h]) * sInv[q * 8 + h];
    const float px = qpts[(size_t)row * 2], py = qpts[(size_t)row * 2 + 1];
    const float vrx = vratio[b * 8 + l * 2], vry = vratio[b * 8 + l * 2 + 1];
    const int Wl = Wl_[l];
    const float fW = (float)Wl;
    const float x = fmaf(px * vrx, fW, ox) - 0.5f;
    const float y = fmaf(py * vry, fW, oy) - 0.5f;
    const float fx = floorf(x), fy = floorf(y);
    const float wx = x - fx, wy = y - fy;
    const int x0 = (int)fx, y0 = (int)fy;
    const int x1 = x0 + 1, y1 = y0 + 1;
    const int xc0 = min(max(x0, 0), Wl - 1), xc1 = min(max(x1, 0), Wl - 1);
    const int yc0 = min(max(y0, 0), Wl - 1), yc1 = min(max(y1, 0), Wl - 1);
    const float ox0 = (x0 >= 0 && x0 < Wl) ? e : 0.f;   // fold attn weight in
    const float ox1 = (x1 >= 0 && x1 < Wl) ? e : 0.f;
    const float oy0 = (y0 >= 0 && y0 < Wl) ? 1.f : 0.f;
    const float oy1 = (y1 >= 0 && y1 < Wl) ? 1.f : 0.f;
    const int base = b * SEQ + st_[l];   // max token idx 43519 < 65536 -> u16 ok
    const int r0 = base + yc0 * Wl, r1 = base + yc1 * Wl;
    uint2 I, Wp;
    I.x = (unsigned int)(r0 + xc0) | ((unsigned int)(r0 + xc1) << 16);
    I.y = (unsigned int)(r1 + xc0) | ((unsigned int)(r1 + xc1) << 16);
    Wp.x = (unsigned int)f2bf((1.f - wx) * (1.f - wy) * ox0 * oy0) |
           ((unsigned int)f2bf(wx * (1.f - wy) * ox1 * oy0) << 16);
    Wp.y = (unsigned int)f2bf((1.f - wx) * wy * ox0 * oy1) |
           ((unsigned int)f2bf(wx * wy * ox1 * oy1) << 16);
    sIdx[(q * 16 + i) * 9 + h] = I;
    sW[(q * 16 + i) * 9 + h] = Wp;
  }
  __syncthreads();  // all off/lg reads for this block's rows complete here

  const int q = t >> 5, sub = t & 31;
  const int h = sub >> 2, dg = sub & 3;
  const int row = row0 + q;
  const bf16* vb = V + (size_t)h * (NROW * 32) + dg * 8;  // head-major base
  const int sb = (q * 16) * 9 + h;
  float a0 = 0.f, a1 = 0.f, a2 = 0.f, a3 = 0.f;
  float a4 = 0.f, a5 = 0.f, a6 = 0.f, a7 = 0.f;

  // prologue: sample 0's metadata + corner loads
  uint2 I = sIdx[sb], Wp = sW[sb];
  uint4 A_ = *(const uint4*)(vb + (size_t)(I.x & 0xffff) * 32);
  uint4 B_ = *(const uint4*)(vb + (size_t)(I.x >> 16) * 32);
  uint4 C_ = *(const uint4*)(vb + (size_t)(I.y & 0xffff) * 32);
  uint4 D_ = *(const uint4*)(vb + (size_t)(I.y >> 16) * 32);

#pragma unroll
  for (int i = 0; i < 16; ++i) {
    const float w0 = bflo(Wp.x), w1 = bfhi(Wp.x);
    const float w2 = bflo(Wp.y), w3 = bfhi(Wp.y);
    uint4 An = A_, Bn = B_, Cn = C_, Dn = D_;
    uint2 In = I, Wn = Wp;
    if (i < 15) {  // issue next sample's loads BEFORE consuming current
      In = sIdx[sb + (i + 1) * 9];
      Wn = sW[sb + (i + 1) * 9];
      An = *(const uint4*)(vb + (size_t)(In.x & 0xffff) * 32);
      Bn = *(const uint4*)(vb + (size_t)(In.x >> 16) * 32);
      Cn = *(const uint4*)(vb + (size_t)(In.y & 0xffff) * 32);
      Dn = *(const uint4*)(vb + (size_t)(In.y >> 16) * 32);
    }
    a0 = fmaf(w0, bflo(A_.x), a0); a1 = fmaf(w0, bfhi(A_.x), a1);
    a2 = fmaf(w0, bflo(A_.y), a2); a3 = fmaf(w0, bfhi(A_.y), a3);
    a4 = fmaf(w0, bflo(A_.z), a4); a5 = fmaf(w0, bfhi(A_.z), a5);
    a6 = fmaf(w0, bflo(A_.w), a6); a7 = fmaf(w0, bfhi(A_.w), a7);
    a0 = fmaf(w1, bflo(B_.x), a0); a1 = fmaf(w1, bfhi(B_.x), a1);
    a2 = fmaf(w1, bflo(B_.y), a2); a3 = fmaf(w1, bfhi(B_.y), a3);
    a4 = fmaf(w1, bflo(B_.z), a4); a5 = fmaf(w1, bfhi(B_.z), a5);
    a6 = fmaf(w1, bflo(B_.w), a6); a7 = fmaf(w1, bfhi(B_.w), a7);
    a0 = fmaf(w2, bflo(C_.x), a0); a1 = fmaf(w2, bfhi(C_.x), a1);
    a2 = fmaf(w2, bflo(C_.y), a2); a3 = fmaf(w2, bfhi(C_.y), a3);
    a4 = fmaf(w2, bflo(C_.z), a4); a5 = fmaf(w2, bfhi(C_.z), a5);
    a6 = fmaf(w2, bflo(C_.w), a6); a7 = fmaf(w2, bfhi(C_.w), a7);
    a0 = fmaf(w3, bflo(D_.x), a0); a1 = fmaf(w3, bfhi(D_.x), a1);
    a2 = fmaf(w3, bflo(D_.y), a2); a3 = fmaf(w3, bfhi(D_.y), a3);
    a4 = fmaf(w3, bflo(D_.z), a4); a5 = fmaf(w3, bfhi(D_.z), a5);
    a6 = fmaf(w3, bflo(D_.w), a6); a7 = fmaf(w3, bfhi(D_.w), a7);
    A_ = An; B_ = Bn; C_ = Cn; D_ = Dn; I = In; Wp = Wn;
  }
  uint4 pk;
  pk.x = (unsigned int)f2bf(a0) | ((unsigned int)f2bf(a1) << 16);
  pk.y = (unsigned int)f2bf(a2) | ((unsigned int)f2bf(a3) << 16);
  pk.z = (unsigned int)f2bf(a4) | ((unsigned int)f2bf(a5) << 16);
  pk.w = (unsigned int)f2bf(a6) | ((unsigned int)f2bf(a7) << 16);
  *(uint4*)((char*)samp + (size_t)row * 512 + (h * 32 + dg * 8) * 2) = pk;
}

// ---------------- K4: upd = samp @ WoutT + bout -> bf16 ---------------------
// (byte-identical to round 15 — proven)
__global__ __launch_bounds__(256) void k_upd(const unsigned short* __restrict__ A,
                                             const unsigned short* __restrict__ Wt,
                                             const float* __restrict__ bias,
                                             bf16* __restrict__ U) {
  __shared__ unsigned short As[64 * 256];  // 32KB, XOR-swizzled
  const int tid = threadIdx.x;
  const int lane = tid & 63, w = tid >> 6;
  const int row0 = blockIdx.x * 64;
#pragma unroll
  for (int it = 0; it < 8; ++it) {
    const int cid = it * 256 + tid;
    const int row = cid >> 5, c = cid & 31;
    const uint4 q = *(const uint4*)(A + (size_t)(row0 + row) * 256 + c * 8);
    *(uint4*)((char*)As + row * 512 + ((c * 16) ^ ((row & 7) << 4))) = q;
  }
  __syncthreads();
  const int lg16 = lane >> 4, l16 = lane & 15;
  f32x4 acc[4][4] = {};
#pragma unroll
  for (int kk = 0; kk < 8; ++kk) {
    bf16x8 af[4], bh[4];
#pragma unroll
    for (int mf = 0; mf < 4; ++mf) {
      const int row = mf * 16 + l16;
      af[mf] = *(const bf16x8*)((const char*)As + row * 512 +
                                ((kk * 64 + lg16 * 16) ^ ((row & 7) << 4)));
    }
#pragma unroll
    for (int nf = 0; nf < 4; ++nf) {
      const int col = w * 64 + nf * 16 + l16;
      bh[nf] = *(const bf16x8*)(Wt + (size_t)col * 256 + kk * 32 + lg16 * 8);
    }
#pragma unroll
    for (int mf = 0; mf < 4; ++mf)
#pragma unroll
      for (int nf = 0; nf < 4; ++nf)
        acc[mf][nf] = __builtin_amdgcn_mfma_f32_16x16x32_bf16(af[mf], bh[nf], acc[mf][nf], 0, 0, 0);
  }
#pragma unroll
  for (int mf = 0; mf < 4; ++mf) {
    const int rbase = row0 + mf * 16 + lg16 * 4;
#pragma unroll
    for (int nf = 0; nf < 4; ++nf) {
      const int col = w * 64 + nf * 16 + l16;
      const float bb = bias[col];
#pragma unroll
      for (int r = 0; r < 4; ++r)
        U[(size_t)(rbase + r) * 256 + col] = __float2bfloat16(acc[mf][nf][r] + bb);
    }
  }
}

// ---------------- K5: y = LN(qf + upd) — SOLE writer of d_out ---------------
__global__ __launch_bounds__(256) void k_ln(const unsigned short* __restrict__ upd,
                                            const float* __restrict__ qf,
                                            const float* __restrict__ gamma,
                                            const float* __restrict__ beta,
                                            float* __restrict__ y) {
  const int w = threadIdx.x >> 6, lane = threadIdx.x & 63;
  const int row = blockIdx.x * 4 + w;
  const int c = lane * 4;
  const ushort4 u = *(const ushort4*)(upd + (size_t)row * 256 + c);
  const float4 qv = *(const float4*)(qf + (size_t)row * 256 + c);
  const float x0 = qv.x + bf2f(u.x);
  const float x1 = qv.y + bf2f(u.y);
  const float x2 = qv.z + bf2f(u.z);
  const float x3 = qv.w + bf2f(u.w);
  float s1 = x0 + x1 + x2 + x3;
  float s2 = x0 * x0 + x1 * x1 + x2 * x2 + x3 * x3;
#pragma unroll
  for (int o = 32; o >= 1; o >>= 1) {
    s1 += __shfl_xor(s1, o);
    s2 += __shfl_xor(s2, o);
  }
  const float mu = s1 * (1.f / 256.f);
  const float var = s2 * (1.f / 256.f) - mu * mu;
  const float rsig = rsqrtf(var + LN_EPS);
  const float4 g = *(const float4*)(gamma + c);
  const float4 bt = *(const float4*)(beta + c);
  float4 o;
  o.x = (x0 - mu) * rsig * g.x + bt.x;
  o.y = (x1 - mu) * rsig * g.y + bt.y;
  o.z = (x2 - mu) * rsig * g.z + bt.z;
  o.w = (x3 - mu) * rsig * g.w + bt.w;
  *(float4*)(y + (size_t)row * 256 + c) = o;
}

extern "C" void kernel_launch(void* const* d_in, const int* in_sizes, int n_in,
                              void* d_out, int out_size, void* d_ws, size_t ws_size,
                              hipStream_t stream) {
  const float* img_feat = (const float*)d_in[0];
  const unsigned char* img_mask = (const unsigned char*)d_in[2];
  const float* vratio = (const float*)d_in[3];
  const float* qf = (const float*)d_in[4];
  const float* qp = (const float*)d_in[5];
  const float* qpts = (const float*)d_in[6];
  const float* Wv = (const float*)d_in[7];
  const float* bv = (const float*)d_in[8];
  const float* Woff = (const float*)d_in[9];
  const float* boff = (const float*)d_in[10];
  const float* Wattn = (const float*)d_in[11];
  const float* battn = (const float*)d_in[12];
  const float* Wout = (const float*)d_in[13];
  const float* bout = (const float*)d_in[14];
  const float* gamma = (const float*)d_in[15];
  const float* beta = (const float*)d_in[16];

  char* ws = (char*)d_ws;
  bf16* V = (bf16*)ws;                                   // 22.3 MB (head-major; reused as upd)
  bf16* off = (bf16*)(ws + (size_t)NROW * 256 * 2);      // 22.3 MB (reused as samp)
  bf16* lg = (bf16*)(ws + (size_t)NROW * 256 * 4);       // 11.1 MB
  unsigned short* wbase =
      (unsigned short*)(ws + (size_t)NROW * 256 * 4 + (size_t)NROW * 128 * 2);
  unsigned short* WvT = wbase;              // 65536 shorts
  unsigned short* WcatT = WvT + 65536;      // 98304 shorts
  unsigned short* WoutT = WcatT + 98304;    // 65536 shorts -> ends 56.16MB (< proven 56.36MB)

  dim3 blk(256);
  k_trans<<<256, blk, 0, stream>>>(Wv, WvT, 256);
  k_trans<<<256, blk, 0, stream>>>(Woff, WcatT, 256);
  k_trans<<<128, blk, 0, stream>>>(Wattn, WcatT + 256 * 256, 128);
  k_trans<<<256, blk, 0, stream>>>(Wout, WoutT, 256);
  k_value<<<NROW / 64, blk, 0, stream>>>(img_feat, WvT, bv, img_mask, V);
  k_offattn<<<NROW / 64, blk, 0, stream>>>(qf, qp, WcatT, boff, battn, off, lg);
  k_sample<<<NROW / QB, blk, 0, stream>>>(V, off, lg, qpts, vratio,
                                          (unsigned short*)off /* samp alias */);
  k_upd<<<NROW / 64, blk, 0, stream>>>((const unsigned short*)off /* samp */, WoutT,
                                       bout, V /* = upd, dead */);
  k_ln<<<NROW / 4, blk, 0, stream>>>((const unsigned short*)V, qf, gamma, beta,
                                     (float*)d_out);
}

// Round 19
// 195.006 us; speedup vs baseline: 1.1283x; 1.1145x over previous
//
#include <hip/hip_runtime.h>
#include <hip/hip_bf16.h>

#define EMB 256
#define SEQ 21760
#define NB 2
#define NROW (NB * SEQ)   // 43520
#define LN_EPS 1e-5f

typedef __hip_bfloat16 bf16;
typedef short bf16x8 __attribute__((ext_vector_type(8)));
typedef float f32x4 __attribute__((ext_vector_type(4)));

__device__ __forceinline__ unsigned short f2bf(float f) {
  __hip_bfloat16 h = __float2bfloat16(f);
  return *reinterpret_cast<unsigned short*>(&h);
}
__device__ __forceinline__ float bf2f(unsigned short u) {
  return __uint_as_float((unsigned int)u << 16);
}
__device__ __forceinline__ float bflo(unsigned int u) { return __uint_as_float(u << 16); }
__device__ __forceinline__ float bfhi(unsigned int u) { return __uint_as_float(u & 0xffff0000u); }

// ---------------- K0: bf16 transpose of W[k][n] -> Wt[n][k] -----------------
__global__ __launch_bounds__(256) void k_trans(const float* __restrict__ src,
                                               unsigned short* __restrict__ dst, int N) {
  const int n = blockIdx.x, k = threadIdx.x;
  dst[n * 256 + k] = f2bf(src[k * N + n]);
}

// ---------------- K1: V = mask ? 0 : (A @ Wt + bias)  -> bf16 HEAD-MAJOR ----
// (byte-identical to round 16 — proven)
__global__ __launch_bounds__(256) void k_value(const float* __restrict__ A,
                                               const unsigned short* __restrict__ Wt,
                                               const float* __restrict__ bias,
                                               const unsigned char* __restrict__ mask,
                                               bf16* __restrict__ V) {
  __shared__ unsigned short As[64 * 256];  // 32KB, XOR-swizzled
  const int tid = threadIdx.x;
  const int lane = tid & 63, w = tid >> 6;
  const int row0 = blockIdx.x * 64;
#pragma unroll
  for (int it = 0; it < 8; ++it) {
    const int cid = it * 256 + tid;
    const int row = cid >> 5, c = cid & 31;
    const float4* p = (const float4*)(A + (size_t)(row0 + row) * 256 + c * 8);
    const float4 a0 = p[0], a1 = p[1];
    union { unsigned short u[8]; uint4 q; } pk;
    pk.u[0] = f2bf(a0.x); pk.u[1] = f2bf(a0.y); pk.u[2] = f2bf(a0.z); pk.u[3] = f2bf(a0.w);
    pk.u[4] = f2bf(a1.x); pk.u[5] = f2bf(a1.y); pk.u[6] = f2bf(a1.z); pk.u[7] = f2bf(a1.w);
    *(uint4*)((char*)As + row * 512 + ((c * 16) ^ ((row & 7) << 4))) = pk.q;
  }
  __syncthreads();
  const int lg16 = lane >> 4, l16 = lane & 15;
  f32x4 acc[4][4] = {};
#pragma unroll
  for (int kk = 0; kk < 8; ++kk) {
    bf16x8 af[4], bh[4];
#pragma unroll
    for (int mf = 0; mf < 4; ++mf) {
      const int row = mf * 16 + l16;
      af[mf] = *(const bf16x8*)((const char*)As + row * 512 +
                                ((kk * 64 + lg16 * 16) ^ ((row & 7) << 4)));
    }
#pragma unroll
    for (int nf = 0; nf < 4; ++nf) {
      const int col = w * 64 + nf * 16 + l16;
      bh[nf] = *(const bf16x8*)(Wt + (size_t)col * 256 + kk * 32 + lg16 * 8);
    }
#pragma unroll
    for (int mf = 0; mf < 4; ++mf)
#pragma unroll
      for (int nf = 0; nf < 4; ++nf)
        acc[mf][nf] = __builtin_amdgcn_mfma_f32_16x16x32_bf16(af[mf], bh[nf], acc[mf][nf], 0, 0, 0);
  }
#pragma unroll
  for (int mf = 0; mf < 4; ++mf) {
    const int rbase = mf * 16 + lg16 * 4;
    const uchar4 mk = *(const uchar4*)(mask + row0 + rbase);
#pragma unroll
    for (int nf = 0; nf < 4; ++nf) {
      const int col = w * 64 + nf * 16 + l16;
      const int hh = col >> 5, ch = col & 31;   // head-major decomposition
      const float bb = bias[col];
#pragma unroll
      for (int r = 0; r < 4; ++r) {
        const unsigned char m = (r == 0) ? mk.x : (r == 1) ? mk.y : (r == 2) ? mk.z : mk.w;
        const float v = m ? 0.f : (acc[mf][nf][r] + bb);
        V[(size_t)hh * (NROW * 32) + (size_t)(row0 + rbase + r) * 32 + ch] =
            __float2bfloat16(v);
      }
    }
  }
}

// ---------------- K2: q = qf+qp; [off|lg] = q @ Wcat -> bf16 ----------------
// (byte-identical to round 11 — proven)
__global__ __launch_bounds__(256) void k_offattn(const float* __restrict__ qf,
                                                 const float* __restrict__ qp,
                                                 const unsigned short* __restrict__ Wt,
                                                 const float* __restrict__ boff,
                                                 const float* __restrict__ battn,
                                                 bf16* __restrict__ off,
                                                 bf16* __restrict__ lg) {
  __shared__ unsigned short As[64 * 256];
  const int tid = threadIdx.x;
  const int lane = tid & 63, w = tid >> 6;
  const int row0 = blockIdx.x * 64;
#pragma unroll
  for (int it = 0; it < 8; ++it) {
    const int cid = it * 256 + tid;
    const int row = cid >> 5, c = cid & 31;
    const float4* pf = (const float4*)(qf + (size_t)(row0 + row) * 256 + c * 8);
    const float4* pp = (const float4*)(qp + (size_t)(row0 + row) * 256 + c * 8);
    const float4 a0 = pf[0], a1 = pf[1], b0 = pp[0], b1 = pp[1];
    union { unsigned short u[8]; uint4 q; } pk;
    pk.u[0] = f2bf(a0.x + b0.x); pk.u[1] = f2bf(a0.y + b0.y);
    pk.u[2] = f2bf(a0.z + b0.z); pk.u[3] = f2bf(a0.w + b0.w);
    pk.u[4] = f2bf(a1.x + b1.x); pk.u[5] = f2bf(a1.y + b1.y);
    pk.u[6] = f2bf(a1.z + b1.z); pk.u[7] = f2bf(a1.w + b1.w);
    *(uint4*)((char*)As + row * 512 + ((c * 16) ^ ((row & 7) << 4))) = pk.q;
  }
  __syncthreads();
  const int lg16 = lane >> 4, l16 = lane & 15;
  f32x4 acc[4][6] = {};
#pragma unroll
  for (int kk = 0; kk < 8; ++kk) {
    bf16x8 af[4], bh[6];
#pragma unroll
    for (int mf = 0; mf < 4; ++mf) {
      const int row = mf * 16 + l16;
      af[mf] = *(const bf16x8*)((const char*)As + row * 512 +
                                ((kk * 64 + lg16 * 16) ^ ((row & 7) << 4)));
    }
#pragma unroll
    for (int nf = 0; nf < 6; ++nf) {
      const int col = w * 96 + nf * 16 + l16;
      bh[nf] = *(const bf16x8*)(Wt + (size_t)col * 256 + kk * 32 + lg16 * 8);
    }
#pragma unroll
    for (int mf = 0; mf < 4; ++mf)
#pragma unroll
      for (int nf = 0; nf < 6; ++nf)
        acc[mf][nf] = __builtin_amdgcn_mfma_f32_16x16x32_bf16(af[mf], bh[nf], acc[mf][nf], 0, 0, 0);
  }
#pragma unroll
  for (int mf = 0; mf < 4; ++mf) {
    const int rbase = row0 + mf * 16 + lg16 * 4;
#pragma unroll
    for (int nf = 0; nf < 6; ++nf) {
      const int col = w * 96 + nf * 16 + l16;
      if (col < 256) {
        const float bb = boff[col];
#pragma unroll
        for (int r = 0; r < 4; ++r)
          off[(size_t)(rbase + r) * 256 + col] = __float2bfloat16(acc[mf][nf][r] + bb);
      } else {
        const float bb = battn[col - 256];
#pragma unroll
        for (int r = 0; r < 4; ++r)
          lg[(size_t)(rbase + r) * 128 + (col - 256)] = __float2bfloat16(acc[mf][nf][r] + bb);
      }
    }
  }
}

// ---------------- K3: softmax + bilinear gather + attn-weighted sum ---------
// HEAD-PARTITIONED: block = (head h = blockIdx&7, 64-query chunk). HW round-
// robins consecutive workgroups across the 8 XCDs, so head i's blocks all land
// on XCD i -> per-XCD V working set = 2.8MB < 4MB L2 (was 22.3MB, thrashing).
// Math is bit-identical to round 16; only the block->work mapping changed.
__global__ __launch_bounds__(256) void k_sample(const bf16* __restrict__ V,
                                                const bf16* __restrict__ off,
                                                const bf16* __restrict__ lg,
                                                const float* __restrict__ qpts,
                                                const float* __restrict__ vratio,
                                                unsigned short* __restrict__ samp) {
  __shared__ uint2 sIdx[64 * 17];  // [q][i(pad 17)] 4x u16 token idx
  __shared__ uint2 sW[64 * 17];    // 4x bf16 premultiplied weights
  __shared__ float sMax[64], sInv[64];
  const int t = threadIdx.x;
  const int h = blockIdx.x & 7;          // head == XCD id under round-robin
  const int row0 = (blockIdx.x >> 3) * 64;

  // ---- phase 0: softmax stats for 64 queries (this head only)
  if (t < 64) {
    const int row = row0 + t;
    const uint4* lp = (const uint4*)(lg + (size_t)row * 128 + h * 16);
    uint4 u0 = lp[0], u1 = lp[1];
    float v[16];
    v[0] = bflo(u0.x); v[1] = bfhi(u0.x); v[2] = bflo(u0.y); v[3] = bfhi(u0.y);
    v[4] = bflo(u0.z); v[5] = bfhi(u0.z); v[6] = bflo(u0.w); v[7] = bfhi(u0.w);
    v[8] = bflo(u1.x); v[9] = bfhi(u1.x); v[10] = bflo(u1.y); v[11] = bfhi(u1.y);
    v[12] = bflo(u1.z); v[13] = bfhi(u1.z); v[14] = bflo(u1.w); v[15] = bfhi(u1.w);
    float m = v[0];
#pragma unroll
    for (int i = 1; i < 16; ++i) m = fmaxf(m, v[i]);
    float s = 0.f;
#pragma unroll
    for (int i = 0; i < 16; ++i) s += __expf(v[i] - m);
    sMax[t] = m;
    sInv[t] = 1.f / s;
  }
  __syncthreads();

  // ---- phase 1: 64q x 16i = 1024 geometry tasks, 4/thread
  const int Wl_[4] = {128, 64, 32, 16};
  const int st_[4] = {0, 16384, 20480, 21504};
#pragma unroll
  for (int tt = 0; tt < 4; ++tt) {
    const int sid = t + tt * 256;
    const int q = sid >> 4, i = sid & 15, l = i >> 2;
    const int row = row0 + q;
    const int b = row >= SEQ;  // NB == 2
    const unsigned int u = *(const unsigned int*)(off + (size_t)row * 256 + (h * 16 + i) * 2);
    const float ox = bflo(u), oy = bfhi(u);
    const float lgv = bf2f(*(const unsigned short*)(lg + (size_t)row * 128 + h * 16 + i));
    const float e = __expf(lgv - sMax[q]) * sInv[q];
    const float px = qpts[(size_t)row * 2], py = qpts[(size_t)row * 2 + 1];
    const float vrx = vratio[b * 8 + l * 2], vry = vratio[b * 8 + l * 2 + 1];
    const int Wl = Wl_[l];
    const float fW = (float)Wl;
    const float x = fmaf(px * vrx, fW, ox) - 0.5f;
    const float y = fmaf(py * vry, fW, oy) - 0.5f;
    const float fx = floorf(x), fy = floorf(y);
    const float wx = x - fx, wy = y - fy;
    const int x0 = (int)fx, y0 = (int)fy;
    const int x1 = x0 + 1, y1 = y0 + 1;
    const int xc0 = min(max(x0, 0), Wl - 1), xc1 = min(max(x1, 0), Wl - 1);
    const int yc0 = min(max(y0, 0), Wl - 1), yc1 = min(max(y1, 0), Wl - 1);
    const float ox0 = (x0 >= 0 && x0 < Wl) ? e : 0.f;   // fold attn weight in
    const float ox1 = (x1 >= 0 && x1 < Wl) ? e : 0.f;
    const float oy0 = (y0 >= 0 && y0 < Wl) ? 1.f : 0.f;
    const float oy1 = (y1 >= 0 && y1 < Wl) ? 1.f : 0.f;
    const int base = b * SEQ + st_[l];   // max token idx 43519 < 65536 -> u16 ok
    const int r0 = base + yc0 * Wl, r1 = base + yc1 * Wl;
    uint2 I, Wp;
    I.x = (unsigned int)(r0 + xc0) | ((unsigned int)(r0 + xc1) << 16);
    I.y = (unsigned int)(r1 + xc0) | ((unsigned int)(r1 + xc1) << 16);
    Wp.x = (unsigned int)f2bf((1.f - wx) * (1.f - wy) * ox0 * oy0) |
           ((unsigned int)f2bf(wx * (1.f - wy) * ox1 * oy0) << 16);
    Wp.y = (unsigned int)f2bf((1.f - wx) * wy * ox0 * oy1) |
           ((unsigned int)f2bf(wx * wy * ox1 * oy1) << 16);
    sIdx[q * 17 + i] = I;
    sW[q * 17 + i] = Wp;
  }
  __syncthreads();

  // ---- phase 2: thread = (q, dg): 8 channels of this head's 32
  const int q = t >> 2, dg = t & 3;
  const int row = row0 + q;
  const bf16* vb = V + (size_t)h * (NROW * 32) + dg * 8;  // head-major base
  float a0 = 0.f, a1 = 0.f, a2 = 0.f, a3 = 0.f;
  float a4 = 0.f, a5 = 0.f, a6 = 0.f, a7 = 0.f;
#pragma unroll
  for (int i = 0; i < 16; ++i) {
    const uint2 I = sIdx[q * 17 + i];
    const uint2 Wp = sW[q * 17 + i];
    const int i0 = I.x & 0xffff, i1 = I.x >> 16;
    const int i2 = I.y & 0xffff, i3 = I.y >> 16;
    const float w0 = bflo(Wp.x), w1 = bfhi(Wp.x);
    const float w2 = bflo(Wp.y), w3 = bfhi(Wp.y);
    {
      const uint4 u = *(const uint4*)(vb + (size_t)i0 * 32);
      a0 = fmaf(w0, bflo(u.x), a0); a1 = fmaf(w0, bfhi(u.x), a1);
      a2 = fmaf(w0, bflo(u.y), a2); a3 = fmaf(w0, bfhi(u.y), a3);
      a4 = fmaf(w0, bflo(u.z), a4); a5 = fmaf(w0, bfhi(u.z), a5);
      a6 = fmaf(w0, bflo(u.w), a6); a7 = fmaf(w0, bfhi(u.w), a7);
    }
    {
      const uint4 u = *(const uint4*)(vb + (size_t)i1 * 32);
      a0 = fmaf(w1, bflo(u.x), a0); a1 = fmaf(w1, bfhi(u.x), a1);
      a2 = fmaf(w1, bflo(u.y), a2); a3 = fmaf(w1, bfhi(u.y), a3);
      a4 = fmaf(w1, bflo(u.z), a4); a5 = fmaf(w1, bfhi(u.z), a5);
      a6 = fmaf(w1, bflo(u.w), a6); a7 = fmaf(w1, bfhi(u.w), a7);
    }
    {
      const uint4 u = *(const uint4*)(vb + (size_t)i2 * 32);
      a0 = fmaf(w2, bflo(u.x), a0); a1 = fmaf(w2, bfhi(u.x), a1);
      a2 = fmaf(w2, bflo(u.y), a2); a3 = fmaf(w2, bfhi(u.y), a3);
      a4 = fmaf(w2, bflo(u.z), a4); a5 = fmaf(w2, bfhi(u.z), a5);
      a6 = fmaf(w2, bflo(u.w), a6); a7 = fmaf(w2, bfhi(u.w), a7);
    }
    {
      const uint4 u = *(const uint4*)(vb + (size_t)i3 * 32);
      a0 = fmaf(w3, bflo(u.x), a0); a1 = fmaf(w3, bfhi(u.x), a1);
      a2 = fmaf(w3, bflo(u.y), a2); a3 = fmaf(w3, bfhi(u.y), a3);
      a4 = fmaf(w3, bflo(u.z), a4); a5 = fmaf(w3, bfhi(u.z), a5);
      a6 = fmaf(w3, bflo(u.w), a6); a7 = fmaf(w3, bfhi(u.w), a7);
    }
  }
  uint4 pk;
  pk.x = (unsigned int)f2bf(a0) | ((unsigned int)f2bf(a1) << 16);
  pk.y = (unsigned int)f2bf(a2) | ((unsigned int)f2bf(a3) << 16);
  pk.z = (unsigned int)f2bf(a4) | ((unsigned int)f2bf(a5) << 16);
  pk.w = (unsigned int)f2bf(a6) | ((unsigned int)f2bf(a7) << 16);
  *(uint4*)((char*)samp + (size_t)row * 512 + (h * 32 + dg * 8) * 2) = pk;
}

// ---------------- K4: upd = samp @ WoutT + bout -> bf16 ---------------------
// (byte-identical to round 15 — proven)
__global__ __launch_bounds__(256) void k_upd(const unsigned short* __restrict__ A,
                                             const unsigned short* __restrict__ Wt,
                                             const float* __restrict__ bias,
                                             bf16* __restrict__ U) {
  __shared__ unsigned short As[64 * 256];  // 32KB, XOR-swizzled
  const int tid = threadIdx.x;
  const int lane = tid & 63, w = tid >> 6;
  const int row0 = blockIdx.x * 64;
#pragma unroll
  for (int it = 0; it < 8; ++it) {
    const int cid = it * 256 + tid;
    const int row = cid >> 5, c = cid & 31;
    const uint4 q = *(const uint4*)(A + (size_t)(row0 + row) * 256 + c * 8);
    *(uint4*)((char*)As + row * 512 + ((c * 16) ^ ((row & 7) << 4))) = q;
  }
  __syncthreads();
  const int lg16 = lane >> 4, l16 = lane & 15;
  f32x4 acc[4][4] = {};
#pragma unroll
  for (int kk = 0; kk < 8; ++kk) {
    bf16x8 af[4], bh[4];
#pragma unroll
    for (int mf = 0; mf < 4; ++mf) {
      const int row = mf * 16 + l16;
      af[mf] = *(const bf16x8*)((const char*)As + row * 512 +
                                ((kk * 64 + lg16 * 16) ^ ((row & 7) << 4)));
    }
#pragma unroll
    for (int nf = 0; nf < 4; ++nf) {
      const int col = w * 64 + nf * 16 + l16;
      bh[nf] = *(const bf16x8*)(Wt + (size_t)col * 256 + kk * 32 + lg16 * 8);
    }
#pragma unroll
    for (int mf = 0; mf < 4; ++mf)
#pragma unroll
      for (int nf = 0; nf < 4; ++nf)
        acc[mf][nf] = __builtin_amdgcn_mfma_f32_16x16x32_bf16(af[mf], bh[nf], acc[mf][nf], 0, 0, 0);
  }
#pragma unroll
  for (int mf = 0; mf < 4; ++mf) {
    const int rbase = row0 + mf * 16 + lg16 * 4;
#pragma unroll
    for (int nf = 0; nf < 4; ++nf) {
      const int col = w * 64 + nf * 16 + l16;
      const float bb = bias[col];
#pragma unroll
      for (int r = 0; r < 4; ++r)
        U[(size_t)(rbase + r) * 256 + col] = __float2bfloat16(acc[mf][nf][r] + bb);
    }
  }
}

// ---------------- K5: y = LN(qf + upd) — SOLE writer of d_out ---------------
__global__ __launch_bounds__(256) void k_ln(const unsigned short* __restrict__ upd,
                                            const float* __restrict__ qf,
                                            const float* __restrict__ gamma,
                                            const float* __restrict__ beta,
                                            float* __restrict__ y) {
  const int w = threadIdx.x >> 6, lane = threadIdx.x & 63;
  const int row = blockIdx.x * 4 + w;
  const int c = lane * 4;
  const ushort4 u = *(const ushort4*)(upd + (size_t)row * 256 + c);
  const float4 qv = *(const float4*)(qf + (size_t)row * 256 + c);
  const float x0 = qv.x + bf2f(u.x);
  const float x1 = qv.y + bf2f(u.y);
  const float x2 = qv.z + bf2f(u.z);
  const float x3 = qv.w + bf2f(u.w);
  float s1 = x0 + x1 + x2 + x3;
  float s2 = x0 * x0 + x1 * x1 + x2 * x2 + x3 * x3;
#pragma unroll
  for (int o = 32; o >= 1; o >>= 1) {
    s1 += __shfl_xor(s1, o);
    s2 += __shfl_xor(s2, o);
  }
  const float mu = s1 * (1.f / 256.f);
  const float var = s2 * (1.f / 256.f) - mu * mu;
  const float rsig = rsqrtf(var + LN_EPS);
  const float4 g = *(const float4*)(gamma + c);
  const float4 bt = *(const float4*)(beta + c);
  float4 o;
  o.x = (x0 - mu) * rsig * g.x + bt.x;
  o.y = (x1 - mu) * rsig * g.y + bt.y;
  o.z = (x2 - mu) * rsig * g.z + bt.z;
  o.w = (x3 - mu) * rsig * g.w + bt.w;
  *(float4*)(y + (size_t)row * 256 + c) = o;
}

extern "C" void kernel_launch(void* const* d_in, const int* in_sizes, int n_in,
                              void* d_out, int out_size, void* d_ws, size_t ws_size,
                              hipStream_t stream) {
  const float* img_feat = (const float*)d_in[0];
  const unsigned char* img_mask = (const unsigned char*)d_in[2];
  const float* vratio = (const float*)d_in[3];
  const float* qf = (const float*)d_in[4];
  const float* qp = (const float*)d_in[5];
  const float* qpts = (const float*)d_in[6];
  const float* Wv = (const float*)d_in[7];
  const float* bv = (const float*)d_in[8];
  const float* Woff = (const float*)d_in[9];
  const float* boff = (const float*)d_in[10];
  const float* Wattn = (const float*)d_in[11];
  const float* battn = (const float*)d_in[12];
  const float* Wout = (const float*)d_in[13];
  const float* bout = (const float*)d_in[14];
  const float* gamma = (const float*)d_in[15];
  const float* beta = (const float*)d_in[16];

  char* ws = (char*)d_ws;
  bf16* V = (bf16*)ws;                                   // 22.3 MB (head-major; reused as upd)
  bf16* off = (bf16*)(ws + (size_t)NROW * 256 * 2);      // 22.3 MB (reused as samp)
  bf16* lg = (bf16*)(ws + (size_t)NROW * 256 * 4);       // 11.1 MB
  unsigned short* wbase =
      (unsigned short*)(ws + (size_t)NROW * 256 * 4 + (size_t)NROW * 128 * 2);
  unsigned short* WvT = wbase;              // 65536 shorts
  unsigned short* WcatT = WvT + 65536;      // 98304 shorts
  unsigned short* WoutT = WcatT + 98304;    // 65536 shorts -> ends 56.16MB (< proven 56.36MB)

  dim3 blk(256);
  k_trans<<<256, blk, 0, stream>>>(Wv, WvT, 256);
  k_trans<<<256, blk, 0, stream>>>(Woff, WcatT, 256);
  k_trans<<<128, blk, 0, stream>>>(Wattn, WcatT + 256 * 256, 128);
  k_trans<<<256, blk, 0, stream>>>(Wout, WoutT, 256);
  k_value<<<NROW / 64, blk, 0, stream>>>(img_feat, WvT, bv, img_mask, V);
  k_offattn<<<NROW / 64, blk, 0, stream>>>(qf, qp, WcatT, boff, battn, off, lg);
  k_sample<<<8 * (NROW / 64), blk, 0, stream>>>(V, off, lg, qpts, vratio,
                                                (unsigned short*)off /* samp alias */);
  k_upd<<<NROW / 64, blk, 0, stream>>>((const unsigned short*)off /* samp */, WoutT,
                                       bout, V /* = upd, dead */);
  k_ln<<<NROW / 4, blk, 0, stream>>>((const unsigned short*)V, qf, gamma, beta,
                                     (float*)d_out);
}

// Round 20
// 186.407 us; speedup vs baseline: 1.1803x; 1.0461x over previous
//
#include <hip/hip_runtime.h>
#include <hip/hip_bf16.h>

#define EMB 256
#define SEQ 21760
#define NB 2
#define NROW (NB * SEQ)   // 43520
#define LN_EPS 1e-5f

typedef __hip_bfloat16 bf16;
typedef short bf16x8 __attribute__((ext_vector_type(8)));
typedef float f32x4 __attribute__((ext_vector_type(4)));

__device__ __forceinline__ unsigned short f2bf(float f) {
  __hip_bfloat16 h = __float2bfloat16(f);
  return *reinterpret_cast<unsigned short*>(&h);
}
__device__ __forceinline__ float bf2f(unsigned short u) {
  return __uint_as_float((unsigned int)u << 16);
}
__device__ __forceinline__ float bflo(unsigned int u) { return __uint_as_float(u << 16); }
__device__ __forceinline__ float bfhi(unsigned int u) { return __uint_as_float(u & 0xffff0000u); }

// v_dot2_f32_bf16: acc += a.lo*b.lo + a.hi*b.hi (bf16 pairs, fp32 accum).
// Guarded: if the builtin is unknown to this toolchain, fall back to fma path.
#if defined(__has_builtin)
#if __has_builtin(__builtin_amdgcn_fdot2_f32_bf16)
#define USE_DOT2 1
#endif
#endif
#ifdef USE_DOT2
__device__ __forceinline__ float dot2bf(unsigned int a, unsigned int b, float c) {
  float d;
  asm("v_dot2_f32_bf16 %0, %1, %2, %3" : "=v"(d) : "v"(a), "v"(b), "v"(c));
  return d;
}
#endif

// ---------------- K0: bf16 transpose of W[k][n] -> Wt[n][k] -----------------
__global__ __launch_bounds__(256) void k_trans(const float* __restrict__ src,
                                               unsigned short* __restrict__ dst, int N) {
  const int n = blockIdx.x, k = threadIdx.x;
  dst[n * 256 + k] = f2bf(src[k * N + n]);
}

// ---------------- K1: V = mask ? 0 : (A @ Wt + bias)  -> bf16 HEAD-MAJOR ----
// (byte-identical to round 16 — proven)
__global__ __launch_bounds__(256) void k_value(const float* __restrict__ A,
                                               const unsigned short* __restrict__ Wt,
                                               const float* __restrict__ bias,
                                               const unsigned char* __restrict__ mask,
                                               bf16* __restrict__ V) {
  __shared__ unsigned short As[64 * 256];  // 32KB, XOR-swizzled
  const int tid = threadIdx.x;
  const int lane = tid & 63, w = tid >> 6;
  const int row0 = blockIdx.x * 64;
#pragma unroll
  for (int it = 0; it < 8; ++it) {
    const int cid = it * 256 + tid;
    const int row = cid >> 5, c = cid & 31;
    const float4* p = (const float4*)(A + (size_t)(row0 + row) * 256 + c * 8);
    const float4 a0 = p[0], a1 = p[1];
    union { unsigned short u[8]; uint4 q; } pk;
    pk.u[0] = f2bf(a0.x); pk.u[1] = f2bf(a0.y); pk.u[2] = f2bf(a0.z); pk.u[3] = f2bf(a0.w);
    pk.u[4] = f2bf(a1.x); pk.u[5] = f2bf(a1.y); pk.u[6] = f2bf(a1.z); pk.u[7] = f2bf(a1.w);
    *(uint4*)((char*)As + row * 512 + ((c * 16) ^ ((row & 7) << 4))) = pk.q;
  }
  __syncthreads();
  const int lg16 = lane >> 4, l16 = lane & 15;
  f32x4 acc[4][4] = {};
#pragma unroll
  for (int kk = 0; kk < 8; ++kk) {
    bf16x8 af[4], bh[4];
#pragma unroll
    for (int mf = 0; mf < 4; ++mf) {
      const int row = mf * 16 + l16;
      af[mf] = *(const bf16x8*)((const char*)As + row * 512 +
                                ((kk * 64 + lg16 * 16) ^ ((row & 7) << 4)));
    }
#pragma unroll
    for (int nf = 0; nf < 4; ++nf) {
      const int col = w * 64 + nf * 16 + l16;
      bh[nf] = *(const bf16x8*)(Wt + (size_t)col * 256 + kk * 32 + lg16 * 8);
    }
#pragma unroll
    for (int mf = 0; mf < 4; ++mf)
#pragma unroll
      for (int nf = 0; nf < 4; ++nf)
        acc[mf][nf] = __builtin_amdgcn_mfma_f32_16x16x32_bf16(af[mf], bh[nf], acc[mf][nf], 0, 0, 0);
  }
#pragma unroll
  for (int mf = 0; mf < 4; ++mf) {
    const int rbase = mf * 16 + lg16 * 4;
    const uchar4 mk = *(const uchar4*)(mask + row0 + rbase);
#pragma unroll
    for (int nf = 0; nf < 4; ++nf) {
      const int col = w * 64 + nf * 16 + l16;
      const int hh = col >> 5, ch = col & 31;   // head-major decomposition
      const float bb = bias[col];
#pragma unroll
      for (int r = 0; r < 4; ++r) {
        const unsigned char m = (r == 0) ? mk.x : (r == 1) ? mk.y : (r == 2) ? mk.z : mk.w;
        const float v = m ? 0.f : (acc[mf][nf][r] + bb);
        V[(size_t)hh * (NROW * 32) + (size_t)(row0 + rbase + r) * 32 + ch] =
            __float2bfloat16(v);
      }
    }
  }
}

// ---------------- K2: q = qf+qp; [off|lg] = q @ Wcat -> bf16 ----------------
// (byte-identical to round 11 — proven)
__global__ __launch_bounds__(256) void k_offattn(const float* __restrict__ qf,
                                                 const float* __restrict__ qp,
                                                 const unsigned short* __restrict__ Wt,
                                                 const float* __restrict__ boff,
                                                 const float* __restrict__ battn,
                                                 bf16* __restrict__ off,
                                                 bf16* __restrict__ lg) {
  __shared__ unsigned short As[64 * 256];
  const int tid = threadIdx.x;
  const int lane = tid & 63, w = tid >> 6;
  const int row0 = blockIdx.x * 64;
#pragma unroll
  for (int it = 0; it < 8; ++it) {
    const int cid = it * 256 + tid;
    const int row = cid >> 5, c = cid & 31;
    const float4* pf = (const float4*)(qf + (size_t)(row0 + row) * 256 + c * 8);
    const float4* pp = (const float4*)(qp + (size_t)(row0 + row) * 256 + c * 8);
    const float4 a0 = pf[0], a1 = pf[1], b0 = pp[0], b1 = pp[1];
    union { unsigned short u[8]; uint4 q; } pk;
    pk.u[0] = f2bf(a0.x + b0.x); pk.u[1] = f2bf(a0.y + b0.y);
    pk.u[2] = f2bf(a0.z + b0.z); pk.u[3] = f2bf(a0.w + b0.w);
    pk.u[4] = f2bf(a1.x + b1.x); pk.u[5] = f2bf(a1.y + b1.y);
    pk.u[6] = f2bf(a1.z + b1.z); pk.u[7] = f2bf(a1.w + b1.w);
    *(uint4*)((char*)As + row * 512 + ((c * 16) ^ ((row & 7) << 4))) = pk.q;
  }
  __syncthreads();
  const int lg16 = lane >> 4, l16 = lane & 15;
  f32x4 acc[4][6] = {};
#pragma unroll
  for (int kk = 0; kk < 8; ++kk) {
    bf16x8 af[4], bh[6];
#pragma unroll
    for (int mf = 0; mf < 4; ++mf) {
      const int row = mf * 16 + l16;
      af[mf] = *(const bf16x8*)((const char*)As + row * 512 +
                                ((kk * 64 + lg16 * 16) ^ ((row & 7) << 4)));
    }
#pragma unroll
    for (int nf = 0; nf < 6; ++nf) {
      const int col = w * 96 + nf * 16 + l16;
      bh[nf] = *(const bf16x8*)(Wt + (size_t)col * 256 + kk * 32 + lg16 * 8);
    }
#pragma unroll
    for (int mf = 0; mf < 4; ++mf)
#pragma unroll
      for (int nf = 0; nf < 6; ++nf)
        acc[mf][nf] = __builtin_amdgcn_mfma_f32_16x16x32_bf16(af[mf], bh[nf], acc[mf][nf], 0, 0, 0);
  }
#pragma unroll
  for (int mf = 0; mf < 4; ++mf) {
    const int rbase = row0 + mf * 16 + lg16 * 4;
#pragma unroll
    for (int nf = 0; nf < 6; ++nf) {
      const int col = w * 96 + nf * 16 + l16;
      if (col < 256) {
        const float bb = boff[col];
#pragma unroll
        for (int r = 0; r < 4; ++r)
          off[(size_t)(rbase + r) * 256 + col] = __float2bfloat16(acc[mf][nf][r] + bb);
      } else {
        const float bb = battn[col - 256];
#pragma unroll
        for (int r = 0; r < 4; ++r)
          lg[(size_t)(rbase + r) * 128 + (col - 256)] = __float2bfloat16(acc[mf][nf][r] + bb);
      }
    }
  }
}

// ---------------- K3: softmax + bilinear gather + attn-weighted sum ---------
// HEAD-PARTITIONED (r19, proven: FETCH 193->60MB). Inner accumulate now uses
// v_perm + v_dot2_f32_bf16 (one instr per corner-pair per channel) when
// available — phase-2 VALU halved. Fallback = r19's proven fma path.
__global__ __launch_bounds__(256) void k_sample(const bf16* __restrict__ V,
                                                const bf16* __restrict__ off,
                                                const bf16* __restrict__ lg,
                                                const float* __restrict__ qpts,
                                                const float* __restrict__ vratio,
                                                unsigned short* __restrict__ samp) {
  __shared__ uint2 sIdx[64 * 17];  // [q][i(pad 17)] 4x u16 token idx
  __shared__ uint2 sW[64 * 17];    // 4x bf16 premultiplied weights
  __shared__ float sMax[64], sInv[64];
  const int t = threadIdx.x;
  const int h = blockIdx.x & 7;          // head == XCD id under round-robin
  const int row0 = (blockIdx.x >> 3) * 64;

  // ---- phase 0: softmax stats for 64 queries (this head only)
  if (t < 64) {
    const int row = row0 + t;
    const uint4* lp = (const uint4*)(lg + (size_t)row * 128 + h * 16);
    uint4 u0 = lp[0], u1 = lp[1];
    float v[16];
    v[0] = bflo(u0.x); v[1] = bfhi(u0.x); v[2] = bflo(u0.y); v[3] = bfhi(u0.y);
    v[4] = bflo(u0.z); v[5] = bfhi(u0.z); v[6] = bflo(u0.w); v[7] = bfhi(u0.w);
    v[8] = bflo(u1.x); v[9] = bfhi(u1.x); v[10] = bflo(u1.y); v[11] = bfhi(u1.y);
    v[12] = bflo(u1.z); v[13] = bfhi(u1.z); v[14] = bflo(u1.w); v[15] = bfhi(u1.w);
    float m = v[0];
#pragma unroll
    for (int i = 1; i < 16; ++i) m = fmaxf(m, v[i]);
    float s = 0.f;
#pragma unroll
    for (int i = 0; i < 16; ++i) s += __expf(v[i] - m);
    sMax[t] = m;
    sInv[t] = 1.f / s;
  }
  __syncthreads();

  // ---- phase 1: 64q x 16i = 1024 geometry tasks, 4/thread
  const int Wl_[4] = {128, 64, 32, 16};
  const int st_[4] = {0, 16384, 20480, 21504};
#pragma unroll
  for (int tt = 0; tt < 4; ++tt) {
    const int sid = t + tt * 256;
    const int q = sid >> 4, i = sid & 15, l = i >> 2;
    const int row = row0 + q;
    const int b = row >= SEQ;  // NB == 2
    const unsigned int u = *(const unsigned int*)(off + (size_t)row * 256 + (h * 16 + i) * 2);
    const float ox = bflo(u), oy = bfhi(u);
    const float lgv = bf2f(*(const unsigned short*)(lg + (size_t)row * 128 + h * 16 + i));
    const float e = __expf(lgv - sMax[q]) * sInv[q];
    const float px = qpts[(size_t)row * 2], py = qpts[(size_t)row * 2 + 1];
    const float vrx = vratio[b * 8 + l * 2], vry = vratio[b * 8 + l * 2 + 1];
    const int Wl = Wl_[l];
    const float fW = (float)Wl;
    const float x = fmaf(px * vrx, fW, ox) - 0.5f;
    const float y = fmaf(py * vry, fW, oy) - 0.5f;
    const float fx = floorf(x), fy = floorf(y);
    const float wx = x - fx, wy = y - fy;
    const int x0 = (int)fx, y0 = (int)fy;
    const int x1 = x0 + 1, y1 = y0 + 1;
    const int xc0 = min(max(x0, 0), Wl - 1), xc1 = min(max(x1, 0), Wl - 1);
    const int yc0 = min(max(y0, 0), Wl - 1), yc1 = min(max(y1, 0), Wl - 1);
    const float ox0 = (x0 >= 0 && x0 < Wl) ? e : 0.f;   // fold attn weight in
    const float ox1 = (x1 >= 0 && x1 < Wl) ? e : 0.f;
    const float oy0 = (y0 >= 0 && y0 < Wl) ? 1.f : 0.f;
    const float oy1 = (y1 >= 0 && y1 < Wl) ? 1.f : 0.f;
    const int base = b * SEQ + st_[l];   // max token idx 43519 < 65536 -> u16 ok
    const int r0 = base + yc0 * Wl, r1 = base + yc1 * Wl;
    uint2 I, Wp;
    I.x = (unsigned int)(r0 + xc0) | ((unsigned int)(r0 + xc1) << 16);
    I.y = (unsigned int)(r1 + xc0) | ((unsigned int)(r1 + xc1) << 16);
    Wp.x = (unsigned int)f2bf((1.f - wx) * (1.f - wy) * ox0 * oy0) |
           ((unsigned int)f2bf(wx * (1.f - wy) * ox1 * oy0) << 16);
    Wp.y = (unsigned int)f2bf((1.f - wx) * wy * ox0 * oy1) |
           ((unsigned int)f2bf(wx * wy * ox1 * oy1) << 16);
    sIdx[q * 17 + i] = I;
    sW[q * 17 + i] = Wp;
  }
  __syncthreads();

  // ---- phase 2: thread = (q, dg): 8 channels of this head's 32
  const int q = t >> 2, dg = t & 3;
  const int row = row0 + q;
  const bf16* vb = V + (size_t)h * (NROW * 32) + dg * 8;  // head-major base
  float a0 = 0.f, a1 = 0.f, a2 = 0.f, a3 = 0.f;
  float a4 = 0.f, a5 = 0.f, a6 = 0.f, a7 = 0.f;
#pragma unroll
  for (int i = 0; i < 16; ++i) {
    const uint2 I = sIdx[q * 17 + i];
    const uint2 Wp = sW[q * 17 + i];
    const int i0 = I.x & 0xffff, i1 = I.x >> 16;
    const int i2 = I.y & 0xffff, i3 = I.y >> 16;
    const uint4 Au = *(const uint4*)(vb + (size_t)i0 * 32);
    const uint4 Bu = *(const uint4*)(vb + (size_t)i1 * 32);
    const uint4 Cu = *(const uint4*)(vb + (size_t)i2 * 32);
    const uint4 Du = *(const uint4*)(vb + (size_t)i3 * 32);
#ifdef USE_DOT2
    // pair channels of corners (A,B) and (C,D); one dot2 per pair
    a0 = dot2bf(__builtin_amdgcn_perm(Bu.x, Au.x, 0x05040100u), Wp.x, a0);
    a1 = dot2bf(__builtin_amdgcn_perm(Bu.x, Au.x, 0x07060302u), Wp.x, a1);
    a2 = dot2bf(__builtin_amdgcn_perm(Bu.y, Au.y, 0x05040100u), Wp.x, a2);
    a3 = dot2bf(__builtin_amdgcn_perm(Bu.y, Au.y, 0x07060302u), Wp.x, a3);
    a4 = dot2bf(__builtin_amdgcn_perm(Bu.z, Au.z, 0x05040100u), Wp.x, a4);
    a5 = dot2bf(__builtin_amdgcn_perm(Bu.z, Au.z, 0x07060302u), Wp.x, a5);
    a6 = dot2bf(__builtin_amdgcn_perm(Bu.w, Au.w, 0x05040100u), Wp.x, a6);
    a7 = dot2bf(__builtin_amdgcn_perm(Bu.w, Au.w, 0x07060302u), Wp.x, a7);
    a0 = dot2bf(__builtin_amdgcn_perm(Du.x, Cu.x, 0x05040100u), Wp.y, a0);
    a1 = dot2bf(__builtin_amdgcn_perm(Du.x, Cu.x, 0x07060302u), Wp.y, a1);
    a2 = dot2bf(__builtin_amdgcn_perm(Du.y, Cu.y, 0x05040100u), Wp.y, a2);
    a3 = dot2bf(__builtin_amdgcn_perm(Du.y, Cu.y, 0x07060302u), Wp.y, a3);
    a4 = dot2bf(__builtin_amdgcn_perm(Du.z, Cu.z, 0x05040100u), Wp.y, a4);
    a5 = dot2bf(__builtin_amdgcn_perm(Du.z, Cu.z, 0x07060302u), Wp.y, a5);
    a6 = dot2bf(__builtin_amdgcn_perm(Du.w, Cu.w, 0x05040100u), Wp.y, a6);
    a7 = dot2bf(__builtin_amdgcn_perm(Du.w, Cu.w, 0x07060302u), Wp.y, a7);
#else
    {
      const float w0 = bflo(Wp.x), w1 = bfhi(Wp.x);
      const float w2 = bflo(Wp.y), w3 = bfhi(Wp.y);
      a0 = fmaf(w0, bflo(Au.x), a0); a1 = fmaf(w0, bfhi(Au.x), a1);
      a2 = fmaf(w0, bflo(Au.y), a2); a3 = fmaf(w0, bfhi(Au.y), a3);
      a4 = fmaf(w0, bflo(Au.z), a4); a5 = fmaf(w0, bfhi(Au.z), a5);
      a6 = fmaf(w0, bflo(Au.w), a6); a7 = fmaf(w0, bfhi(Au.w), a7);
      a0 = fmaf(w1, bflo(Bu.x), a0); a1 = fmaf(w1, bfhi(Bu.x), a1);
      a2 = fmaf(w1, bflo(Bu.y), a2); a3 = fmaf(w1, bfhi(Bu.y), a3);
      a4 = fmaf(w1, bflo(Bu.z), a4); a5 = fmaf(w1, bfhi(Bu.z), a5);
      a6 = fmaf(w1, bflo(Bu.w), a6); a7 = fmaf(w1, bfhi(Bu.w), a7);
      a0 = fmaf(w2, bflo(Cu.x), a0); a1 = fmaf(w2, bfhi(Cu.x), a1);
      a2 = fmaf(w2, bflo(Cu.y), a2); a3 = fmaf(w2, bfhi(Cu.y), a3);
      a4 = fmaf(w2, bflo(Cu.z), a4); a5 = fmaf(w2, bfhi(Cu.z), a5);
      a6 = fmaf(w2, bflo(Cu.w), a6); a7 = fmaf(w2, bfhi(Cu.w), a7);
      a0 = fmaf(w3, bflo(Du.x), a0); a1 = fmaf(w3, bfhi(Du.x), a1);
      a2 = fmaf(w3, bflo(Du.y), a2); a3 = fmaf(w3, bfhi(Du.y), a3);
      a4 = fmaf(w3, bflo(Du.z), a4); a5 = fmaf(w3, bfhi(Du.z), a5);
      a6 = fmaf(w3, bflo(Du.w), a6); a7 = fmaf(w3, bfhi(Du.w), a7);
    }
#endif
  }
  uint4 pk;
  pk.x = (unsigned int)f2bf(a0) | ((unsigned int)f2bf(a1) << 16);
  pk.y = (unsigned int)f2bf(a2) | ((unsigned int)f2bf(a3) << 16);
  pk.z = (unsigned int)f2bf(a4) | ((unsigned int)f2bf(a5) << 16);
  pk.w = (unsigned int)f2bf(a6) | ((unsigned int)f2bf(a7) << 16);
  *(uint4*)((char*)samp + (size_t)row * 512 + (h * 32 + dg * 8) * 2) = pk;
}

// ---------------- K4: upd = samp @ WoutT + bout -> bf16 ---------------------
// (byte-identical to round 15 — proven)
__global__ __launch_bounds__(256) void k_upd(const unsigned short* __restrict__ A,
                                             const unsigned short* __restrict__ Wt,
                                             const float* __restrict__ bias,
                                             bf16* __restrict__ U) {
  __shared__ unsigned short As[64 * 256];  // 32KB, XOR-swizzled
  const int tid = threadIdx.x;
  const int lane = tid & 63, w = tid >> 6;
  const int row0 = blockIdx.x * 64;
#pragma unroll
  for (int it = 0; it < 8; ++it) {
    const int cid = it * 256 + tid;
    const int row = cid >> 5, c = cid & 31;
    const uint4 q = *(const uint4*)(A + (size_t)(row0 + row) * 256 + c * 8);
    *(uint4*)((char*)As + row * 512 + ((c * 16) ^ ((row & 7) << 4))) = q;
  }
  __syncthreads();
  const int lg16 = lane >> 4, l16 = lane & 15;
  f32x4 acc[4][4] = {};
#pragma unroll
  for (int kk = 0; kk < 8; ++kk) {
    bf16x8 af[4], bh[4];
#pragma unroll
    for (int mf = 0; mf < 4; ++mf) {
      const int row = mf * 16 + l16;
      af[mf] = *(const bf16x8*)((const char*)As + row * 512 +
                                ((kk * 64 + lg16 * 16) ^ ((row & 7) << 4)));
    }
#pragma unroll
    for (int nf = 0; nf < 4; ++nf) {
      const int col = w * 64 + nf * 16 + l16;
      bh[nf] = *(const bf16x8*)(Wt + (size_t)col * 256 + kk * 32 + lg16 * 8);
    }
#pragma unroll
    for (int mf = 0; mf < 4; ++mf)
#pragma unroll
      for (int nf = 0; nf < 4; ++nf)
        acc[mf][nf] = __builtin_amdgcn_mfma_f32_16x16x32_bf16(af[mf], bh[nf], acc[mf][nf], 0, 0, 0);
  }
#pragma unroll
  for (int mf = 0; mf < 4; ++mf) {
    const int rbase = row0 + mf * 16 + lg16 * 4;
#pragma unroll
    for (int nf = 0; nf < 4; ++nf) {
      const int col = w * 64 + nf * 16 + l16;
      const float bb = bias[col];
#pragma unroll
      for (int r = 0; r < 4; ++r)
        U[(size_t)(rbase + r) * 256 + col] = __float2bfloat16(acc[mf][nf][r] + bb);
    }
  }
}

// ---------------- K5: y = LN(qf + upd) — SOLE writer of d_out ---------------
__global__ __launch_bounds__(256) void k_ln(const unsigned short* __restrict__ upd,
                                            const float* __restrict__ qf,
                                            const float* __restrict__ gamma,
                                            const float* __restrict__ beta,
                                            float* __restrict__ y) {
  const int w = threadIdx.x >> 6, lane = threadIdx.x & 63;
  const int row = blockIdx.x * 4 + w;
  const int c = lane * 4;
  const ushort4 u = *(const ushort4*)(upd + (size_t)row * 256 + c);
  const float4 qv = *(const float4*)(qf + (size_t)row * 256 + c);
  const float x0 = qv.x + bf2f(u.x);
  const float x1 = qv.y + bf2f(u.y);
  const float x2 = qv.z + bf2f(u.z);
  const float x3 = qv.w + bf2f(u.w);
  float s1 = x0 + x1 + x2 + x3;
  float s2 = x0 * x0 + x1 * x1 + x2 * x2 + x3 * x3;
#pragma unroll
  for (int o = 32; o >= 1; o >>= 1) {
    s1 += __shfl_xor(s1, o);
    s2 += __shfl_xor(s2, o);
  }
  const float mu = s1 * (1.f / 256.f);
  const float var = s2 * (1.f / 256.f) - mu * mu;
  const float rsig = rsqrtf(var + LN_EPS);
  const float4 g = *(const float4*)(gamma + c);
  const float4 bt = *(const float4*)(beta + c);
  float4 o;
  o.x = (x0 - mu) * rsig * g.x + bt.x;
  o.y = (x1 - mu) * rsig * g.y + bt.y;
  o.z = (x2 - mu) * rsig * g.z + bt.z;
  o.w = (x3 - mu) * rsig * g.w + bt.w;
  *(float4*)(y + (size_t)row * 256 + c) = o;
}

extern "C" void kernel_launch(void* const* d_in, const int* in_sizes, int n_in,
                              void* d_out, int out_size, void* d_ws, size_t ws_size,
                              hipStream_t stream) {
  const float* img_feat = (const float*)d_in[0];
  const unsigned char* img_mask = (const unsigned char*)d_in[2];
  const float* vratio = (const float*)d_in[3];
  const float* qf = (const float*)d_in[4];
  const float* qp = (const float*)d_in[5];
  const float* qpts = (const float*)d_in[6];
  const float* Wv = (const float*)d_in[7];
  const float* bv = (const float*)d_in[8];
  const float* Woff = (const float*)d_in[9];
  const float* boff = (const float*)d_in[10];
  const float* Wattn = (const float*)d_in[11];
  const float* battn = (const float*)d_in[12];
  const float* Wout = (const float*)d_in[13];
  const float* bout = (const float*)d_in[14];
  const float* gamma = (const float*)d_in[15];
  const float* beta = (const float*)d_in[16];

  char* ws = (char*)d_ws;
  bf16* V = (bf16*)ws;                                   // 22.3 MB (head-major; reused as upd)
  bf16* off = (bf16*)(ws + (size_t)NROW * 256 * 2);      // 22.3 MB (reused as samp)
  bf16* lg = (bf16*)(ws + (size_t)NROW * 256 * 4);       // 11.1 MB
  unsigned short* wbase =
      (unsigned short*)(ws + (size_t)NROW * 256 * 4 + (size_t)NROW * 128 * 2);
  unsigned short* WvT = wbase;              // 65536 shorts
  unsigned short* WcatT = WvT + 65536;      // 98304 shorts
  unsigned short* WoutT = WcatT + 98304;    // 65536 shorts -> ends 56.16MB (< proven 56.36MB)

  dim3 blk(256);
  k_trans<<<256, blk, 0, stream>>>(Wv, WvT, 256);
  k_trans<<<256, blk, 0, stream>>>(Woff, WcatT, 256);
  k_trans<<<128, blk, 0, stream>>>(Wattn, WcatT + 256 * 256, 128);
  k_trans<<<256, blk, 0, stream>>>(Wout, WoutT, 256);
  k_value<<<NROW / 64, blk, 0, stream>>>(img_feat, WvT, bv, img_mask, V);
  k_offattn<<<NROW / 64, blk, 0, stream>>>(qf, qp, WcatT, boff, battn, off, lg);
  k_sample<<<8 * (NROW / 64), blk, 0, stream>>>(V, off, lg, qpts, vratio,
                                                (unsigned short*)off /* samp alias */);
  k_upd<<<NROW / 64, blk, 0, stream>>>((const unsigned short*)off /* samp */, WoutT,
                                       bout, V /* = upd, dead */);
  k_ln<<<NROW / 4, blk, 0, stream>>>((const unsigned short*)V, qf, gamma, beta,
                                     (float*)d_out);
}

// Round 21
// 177.944 us; speedup vs baseline: 1.2364x; 1.0476x over previous
//
#include <hip/hip_runtime.h>
#include <hip/hip_bf16.h>

#define EMB 256
#define SEQ 21760
#define NB 2
#define NROW (NB * SEQ)   // 43520
#define LN_EPS 1e-5f

typedef __hip_bfloat16 bf16;
typedef short bf16x8 __attribute__((ext_vector_type(8)));
typedef float f32x4 __attribute__((ext_vector_type(4)));

__device__ __forceinline__ unsigned short f2bf(float f) {
  __hip_bfloat16 h = __float2bfloat16(f);
  return *reinterpret_cast<unsigned short*>(&h);
}
__device__ __forceinline__ float bf2f(unsigned short u) {
  return __uint_as_float((unsigned int)u << 16);
}
__device__ __forceinline__ float bflo(unsigned int u) { return __uint_as_float(u << 16); }
__device__ __forceinline__ float bfhi(unsigned int u) { return __uint_as_float(u & 0xffff0000u); }

#if defined(__has_builtin)
#if __has_builtin(__builtin_amdgcn_fdot2_f32_bf16)
#define USE_DOT2 1
#endif
#endif
#ifdef USE_DOT2
__device__ __forceinline__ float dot2bf(unsigned int a, unsigned int b, float c) {
  float d;
  asm("v_dot2_f32_bf16 %0, %1, %2, %3" : "=v"(d) : "v"(a), "v"(b), "v"(c));
  return d;
}
#endif

// ---------------- K0: all 4 weight transposes in ONE launch -----------------
// blocks [0,256): Wv->WvT | [256,512): Woff->WcatT | [512,640): Wattn->WcatT+64K
// | [640,896): Wout->WoutT
__global__ __launch_bounds__(256) void k_trans_all(const float* __restrict__ Wv,
                                                   const float* __restrict__ Woff,
                                                   const float* __restrict__ Wattn,
                                                   const float* __restrict__ Wout,
                                                   unsigned short* __restrict__ WvT,
                                                   unsigned short* __restrict__ WcatT,
                                                   unsigned short* __restrict__ WoutT) {
  const int bid = blockIdx.x, k = threadIdx.x;
  if (bid < 256) {
    WvT[bid * 256 + k] = f2bf(Wv[k * 256 + bid]);
  } else if (bid < 512) {
    const int n = bid - 256;
    WcatT[n * 256 + k] = f2bf(Woff[k * 256 + n]);
  } else if (bid < 640) {
    const int n = bid - 512;
    WcatT[(256 + n) * 256 + k] = f2bf(Wattn[k * 128 + n]);
  } else {
    const int n = bid - 640;
    WoutT[n * 256 + k] = f2bf(Wout[k * 256 + n]);
  }
}

// ---------------- K1: V = mask ? 0 : (A @ Wt + bias)  -> bf16 HEAD-MAJOR ----
// (byte-identical to round 16 — proven)
__global__ __launch_bounds__(256) void k_value(const float* __restrict__ A,
                                               const unsigned short* __restrict__ Wt,
                                               const float* __restrict__ bias,
                                               const unsigned char* __restrict__ mask,
                                               bf16* __restrict__ V) {
  __shared__ unsigned short As[64 * 256];  // 32KB, XOR-swizzled
  const int tid = threadIdx.x;
  const int lane = tid & 63, w = tid >> 6;
  const int row0 = blockIdx.x * 64;
#pragma unroll
  for (int it = 0; it < 8; ++it) {
    const int cid = it * 256 + tid;
    const int row = cid >> 5, c = cid & 31;
    const float4* p = (const float4*)(A + (size_t)(row0 + row) * 256 + c * 8);
    const float4 a0 = p[0], a1 = p[1];
    union { unsigned short u[8]; uint4 q; } pk;
    pk.u[0] = f2bf(a0.x); pk.u[1] = f2bf(a0.y); pk.u[2] = f2bf(a0.z); pk.u[3] = f2bf(a0.w);
    pk.u[4] = f2bf(a1.x); pk.u[5] = f2bf(a1.y); pk.u[6] = f2bf(a1.z); pk.u[7] = f2bf(a1.w);
    *(uint4*)((char*)As + row * 512 + ((c * 16) ^ ((row & 7) << 4))) = pk.q;
  }
  __syncthreads();
  const int lg16 = lane >> 4, l16 = lane & 15;
  f32x4 acc[4][4] = {};
#pragma unroll
  for (int kk = 0; kk < 8; ++kk) {
    bf16x8 af[4], bh[4];
#pragma unroll
    for (int mf = 0; mf < 4; ++mf) {
      const int row = mf * 16 + l16;
      af[mf] = *(const bf16x8*)((const char*)As + row * 512 +
                                ((kk * 64 + lg16 * 16) ^ ((row & 7) << 4)));
    }
#pragma unroll
    for (int nf = 0; nf < 4; ++nf) {
      const int col = w * 64 + nf * 16 + l16;
      bh[nf] = *(const bf16x8*)(Wt + (size_t)col * 256 + kk * 32 + lg16 * 8);
    }
#pragma unroll
    for (int mf = 0; mf < 4; ++mf)
#pragma unroll
      for (int nf = 0; nf < 4; ++nf)
        acc[mf][nf] = __builtin_amdgcn_mfma_f32_16x16x32_bf16(af[mf], bh[nf], acc[mf][nf], 0, 0, 0);
  }
#pragma unroll
  for (int mf = 0; mf < 4; ++mf) {
    const int rbase = mf * 16 + lg16 * 4;
    const uchar4 mk = *(const uchar4*)(mask + row0 + rbase);
#pragma unroll
    for (int nf = 0; nf < 4; ++nf) {
      const int col = w * 64 + nf * 16 + l16;
      const int hh = col >> 5, ch = col & 31;   // head-major decomposition
      const float bb = bias[col];
#pragma unroll
      for (int r = 0; r < 4; ++r) {
        const unsigned char m = (r == 0) ? mk.x : (r == 1) ? mk.y : (r == 2) ? mk.z : mk.w;
        const float v = m ? 0.f : (acc[mf][nf][r] + bb);
        V[(size_t)hh * (NROW * 32) + (size_t)(row0 + rbase + r) * 32 + ch] =
            __float2bfloat16(v);
      }
    }
  }
}

// ---------------- K2: q = qf+qp; [off|lg] = q @ Wcat -> bf16 ----------------
// (byte-identical to round 11 — proven)
__global__ __launch_bounds__(256) void k_offattn(const float* __restrict__ qf,
                                                 const float* __restrict__ qp,
                                                 const unsigned short* __restrict__ Wt,
                                                 const float* __restrict__ boff,
                                                 const float* __restrict__ battn,
                                                 bf16* __restrict__ off,
                                                 bf16* __restrict__ lg) {
  __shared__ unsigned short As[64 * 256];
  const int tid = threadIdx.x;
  const int lane = tid & 63, w = tid >> 6;
  const int row0 = blockIdx.x * 64;
#pragma unroll
  for (int it = 0; it < 8; ++it) {
    const int cid = it * 256 + tid;
    const int row = cid >> 5, c = cid & 31;
    const float4* pf = (const float4*)(qf + (size_t)(row0 + row) * 256 + c * 8);
    const float4* pp = (const float4*)(qp + (size_t)(row0 + row) * 256 + c * 8);
    const float4 a0 = pf[0], a1 = pf[1], b0 = pp[0], b1 = pp[1];
    union { unsigned short u[8]; uint4 q; } pk;
    pk.u[0] = f2bf(a0.x + b0.x); pk.u[1] = f2bf(a0.y + b0.y);
    pk.u[2] = f2bf(a0.z + b0.z); pk.u[3] = f2bf(a0.w + b0.w);
    pk.u[4] = f2bf(a1.x + b1.x); pk.u[5] = f2bf(a1.y + b1.y);
    pk.u[6] = f2bf(a1.z + b1.z); pk.u[7] = f2bf(a1.w + b1.w);
    *(uint4*)((char*)As + row * 512 + ((c * 16) ^ ((row & 7) << 4))) = pk.q;
  }
  __syncthreads();
  const int lg16 = lane >> 4, l16 = lane & 15;
  f32x4 acc[4][6] = {};
#pragma unroll
  for (int kk = 0; kk < 8; ++kk) {
    bf16x8 af[4], bh[6];
#pragma unroll
    for (int mf = 0; mf < 4; ++mf) {
      const int row = mf * 16 + l16;
      af[mf] = *(const bf16x8*)((const char*)As + row * 512 +
                                ((kk * 64 + lg16 * 16) ^ ((row & 7) << 4)));
    }
#pragma unroll
    for (int nf = 0; nf < 6; ++nf) {
      const int col = w * 96 + nf * 16 + l16;
      bh[nf] = *(const bf16x8*)(Wt + (size_t)col * 256 + kk * 32 + lg16 * 8);
    }
#pragma unroll
    for (int mf = 0; mf < 4; ++mf)
#pragma unroll
      for (int nf = 0; nf < 6; ++nf)
        acc[mf][nf] = __builtin_amdgcn_mfma_f32_16x16x32_bf16(af[mf], bh[nf], acc[mf][nf], 0, 0, 0);
  }
#pragma unroll
  for (int mf = 0; mf < 4; ++mf) {
    const int rbase = row0 + mf * 16 + lg16 * 4;
#pragma unroll
    for (int nf = 0; nf < 6; ++nf) {
      const int col = w * 96 + nf * 16 + l16;
      if (col < 256) {
        const float bb = boff[col];
#pragma unroll
        for (int r = 0; r < 4; ++r)
          off[(size_t)(rbase + r) * 256 + col] = __float2bfloat16(acc[mf][nf][r] + bb);
      } else {
        const float bb = battn[col - 256];
#pragma unroll
        for (int r = 0; r < 4; ++r)
          lg[(size_t)(rbase + r) * 128 + (col - 256)] = __float2bfloat16(acc[mf][nf][r] + bb);
      }
    }
  }
}

// ---------------- K3: softmax + bilinear gather + attn-weighted sum ---------
// HEAD-PARTITIONED (r19) + dot2 (r20). sIdx now holds PRE-SCALED BYTE OFFSETS
// (uint4, one ds_read_b128/sample) — kills and/shl addressing per corner.
__global__ __launch_bounds__(256) void k_sample(const bf16* __restrict__ V,
                                                const bf16* __restrict__ off,
                                                const bf16* __restrict__ lg,
                                                const float* __restrict__ qpts,
                                                const float* __restrict__ vratio,
                                                unsigned short* __restrict__ samp) {
  __shared__ uint4 sIdx[64 * 17];  // [q][i(pad 17)] 4x u32 BYTE offsets
  __shared__ uint2 sW[64 * 17];    // 4x bf16 premultiplied weights
  __shared__ float sMax[64], sInv[64];
  const int t = threadIdx.x;
  const int h = blockIdx.x & 7;          // head == XCD id under round-robin
  const int row0 = (blockIdx.x >> 3) * 64;

  // ---- phase 0: softmax stats for 64 queries (this head only)
  if (t < 64) {
    const int row = row0 + t;
    const uint4* lp = (const uint4*)(lg + (size_t)row * 128 + h * 16);
    uint4 u0 = lp[0], u1 = lp[1];
    float v[16];
    v[0] = bflo(u0.x); v[1] = bfhi(u0.x); v[2] = bflo(u0.y); v[3] = bfhi(u0.y);
    v[4] = bflo(u0.z); v[5] = bfhi(u0.z); v[6] = bflo(u0.w); v[7] = bfhi(u0.w);
    v[8] = bflo(u1.x); v[9] = bfhi(u1.x); v[10] = bflo(u1.y); v[11] = bfhi(u1.y);
    v[12] = bflo(u1.z); v[13] = bfhi(u1.z); v[14] = bflo(u1.w); v[15] = bfhi(u1.w);
    float m = v[0];
#pragma unroll
    for (int i = 1; i < 16; ++i) m = fmaxf(m, v[i]);
    float s = 0.f;
#pragma unroll
    for (int i = 0; i < 16; ++i) s += __expf(v[i] - m);
    sMax[t] = m;
    sInv[t] = 1.f / s;
  }
  __syncthreads();

  // ---- phase 1: 64q x 16i = 1024 geometry tasks, 4/thread
  const int Wl_[4] = {128, 64, 32, 16};
  const int st_[4] = {0, 16384, 20480, 21504};
#pragma unroll
  for (int tt = 0; tt < 4; ++tt) {
    const int sid = t + tt * 256;
    const int q = sid >> 4, i = sid & 15, l = i >> 2;
    const int row = row0 + q;
    const int b = row >= SEQ;  // NB == 2
    const unsigned int u = *(const unsigned int*)(off + (size_t)row * 256 + (h * 16 + i) * 2);
    const float ox = bflo(u), oy = bfhi(u);
    const float lgv = bf2f(*(const unsigned short*)(lg + (size_t)row * 128 + h * 16 + i));
    const float e = __expf(lgv - sMax[q]) * sInv[q];
    const float px = qpts[(size_t)row * 2], py = qpts[(size_t)row * 2 + 1];
    const float vrx = vratio[b * 8 + l * 2], vry = vratio[b * 8 + l * 2 + 1];
    const int Wl = Wl_[l];
    const float fW = (float)Wl;
    const float x = fmaf(px * vrx, fW, ox) - 0.5f;
    const float y = fmaf(py * vry, fW, oy) - 0.5f;
    const float fx = floorf(x), fy = floorf(y);
    const float wx = x - fx, wy = y - fy;
    const int x0 = (int)fx, y0 = (int)fy;
    const int x1 = x0 + 1, y1 = y0 + 1;
    const int xc0 = min(max(x0, 0), Wl - 1), xc1 = min(max(x1, 0), Wl - 1);
    const int yc0 = min(max(y0, 0), Wl - 1), yc1 = min(max(y1, 0), Wl - 1);
    const float ox0 = (x0 >= 0 && x0 < Wl) ? e : 0.f;   // fold attn weight in
    const float ox1 = (x1 >= 0 && x1 < Wl) ? e : 0.f;
    const float oy0 = (y0 >= 0 && y0 < Wl) ? 1.f : 0.f;
    const float oy1 = (y1 >= 0 && y1 < Wl) ? 1.f : 0.f;
    const int base = b * SEQ + st_[l];
    const int r0 = base + yc0 * Wl, r1 = base + yc1 * Wl;
    uint4 I4;                      // byte offsets: token * 32ch * 2B = token*64
    I4.x = (unsigned int)(r0 + xc0) << 6;
    I4.y = (unsigned int)(r0 + xc1) << 6;
    I4.z = (unsigned int)(r1 + xc0) << 6;
    I4.w = (unsigned int)(r1 + xc1) << 6;
    uint2 Wp;
    Wp.x = (unsigned int)f2bf((1.f - wx) * (1.f - wy) * ox0 * oy0) |
           ((unsigned int)f2bf(wx * (1.f - wy) * ox1 * oy0) << 16);
    Wp.y = (unsigned int)f2bf((1.f - wx) * wy * ox0 * oy1) |
           ((unsigned int)f2bf(wx * wy * ox1 * oy1) << 16);
    sIdx[q * 17 + i] = I4;
    sW[q * 17 + i] = Wp;
  }
  __syncthreads();

  // ---- phase 2: thread = (q, dg): 8 channels of this head's 32
  const int q = t >> 2, dg = t & 3;
  const int row = row0 + q;
  const char* vbase = (const char*)(V + (size_t)h * (NROW * 32)) + dg * 16;
  float a0 = 0.f, a1 = 0.f, a2 = 0.f, a3 = 0.f;
  float a4 = 0.f, a5 = 0.f, a6 = 0.f, a7 = 0.f;
#pragma unroll
  for (int i = 0; i < 16; ++i) {
    const uint4 I4 = sIdx[q * 17 + i];
    const uint2 Wp = sW[q * 17 + i];
    const uint4 Au = *(const uint4*)(vbase + I4.x);
    const uint4 Bu = *(const uint4*)(vbase + I4.y);
    const uint4 Cu = *(const uint4*)(vbase + I4.z);
    const uint4 Du = *(const uint4*)(vbase + I4.w);
#ifdef USE_DOT2
    a0 = dot2bf(__builtin_amdgcn_perm(Bu.x, Au.x, 0x05040100u), Wp.x, a0);
    a1 = dot2bf(__builtin_amdgcn_perm(Bu.x, Au.x, 0x07060302u), Wp.x, a1);
    a2 = dot2bf(__builtin_amdgcn_perm(Bu.y, Au.y, 0x05040100u), Wp.x, a2);
    a3 = dot2bf(__builtin_amdgcn_perm(Bu.y, Au.y, 0x07060302u), Wp.x, a3);
    a4 = dot2bf(__builtin_amdgcn_perm(Bu.z, Au.z, 0x05040100u), Wp.x, a4);
    a5 = dot2bf(__builtin_amdgcn_perm(Bu.z, Au.z, 0x07060302u), Wp.x, a5);
    a6 = dot2bf(__builtin_amdgcn_perm(Bu.w, Au.w, 0x05040100u), Wp.x, a6);
    a7 = dot2bf(__builtin_amdgcn_perm(Bu.w, Au.w, 0x07060302u), Wp.x, a7);
    a0 = dot2bf(__builtin_amdgcn_perm(Du.x, Cu.x, 0x05040100u), Wp.y, a0);
    a1 = dot2bf(__builtin_amdgcn_perm(Du.x, Cu.x, 0x07060302u), Wp.y, a1);
    a2 = dot2bf(__builtin_amdgcn_perm(Du.y, Cu.y, 0x05040100u), Wp.y, a2);
    a3 = dot2bf(__builtin_amdgcn_perm(Du.y, Cu.y, 0x07060302u), Wp.y, a3);
    a4 = dot2bf(__builtin_amdgcn_perm(Du.z, Cu.z, 0x05040100u), Wp.y, a4);
    a5 = dot2bf(__builtin_amdgcn_perm(Du.z, Cu.z, 0x07060302u), Wp.y, a5);
    a6 = dot2bf(__builtin_amdgcn_perm(Du.w, Cu.w, 0x05040100u), Wp.y, a6);
    a7 = dot2bf(__builtin_amdgcn_perm(Du.w, Cu.w, 0x07060302u), Wp.y, a7);
#else
    {
      const float w0 = bflo(Wp.x), w1 = bfhi(Wp.x);
      const float w2 = bflo(Wp.y), w3 = bfhi(Wp.y);
      a0 = fmaf(w0, bflo(Au.x), a0); a1 = fmaf(w0, bfhi(Au.x), a1);
      a2 = fmaf(w0, bflo(Au.y), a2); a3 = fmaf(w0, bfhi(Au.y), a3);
      a4 = fmaf(w0, bflo(Au.z), a4); a5 = fmaf(w0, bfhi(Au.z), a5);
      a6 = fmaf(w0, bflo(Au.w), a6); a7 = fmaf(w0, bfhi(Au.w), a7);
      a0 = fmaf(w1, bflo(Bu.x), a0); a1 = fmaf(w1, bfhi(Bu.x), a1);
      a2 = fmaf(w1, bflo(Bu.y), a2); a3 = fmaf(w1, bfhi(Bu.y), a3);
      a4 = fmaf(w1, bflo(Bu.z), a4); a5 = fmaf(w1, bfhi(Bu.z), a5);
      a6 = fmaf(w1, bflo(Bu.w), a6); a7 = fmaf(w1, bfhi(Bu.w), a7);
      a0 = fmaf(w2, bflo(Cu.x), a0); a1 = fmaf(w2, bfhi(Cu.x), a1);
      a2 = fmaf(w2, bflo(Cu.y), a2); a3 = fmaf(w2, bfhi(Cu.y), a3);
      a4 = fmaf(w2, bflo(Cu.z), a4); a5 = fmaf(w2, bfhi(Cu.z), a5);
      a6 = fmaf(w2, bflo(Cu.w), a6); a7 = fmaf(w2, bfhi(Cu.w), a7);
      a0 = fmaf(w3, bflo(Du.x), a0); a1 = fmaf(w3, bfhi(Du.x), a1);
      a2 = fmaf(w3, bflo(Du.y), a2); a3 = fmaf(w3, bfhi(Du.y), a3);
      a4 = fmaf(w3, bflo(Du.z), a4); a5 = fmaf(w3, bfhi(Du.z), a5);
      a6 = fmaf(w3, bflo(Du.w), a6); a7 = fmaf(w3, bfhi(Du.w), a7);
    }
#endif
  }
  uint4 pk;
  pk.x = (unsigned int)f2bf(a0) | ((unsigned int)f2bf(a1) << 16);
  pk.y = (unsigned int)f2bf(a2) | ((unsigned int)f2bf(a3) << 16);
  pk.z = (unsigned int)f2bf(a4) | ((unsigned int)f2bf(a5) << 16);
  pk.w = (unsigned int)f2bf(a6) | ((unsigned int)f2bf(a7) << 16);
  *(uint4*)((char*)samp + (size_t)row * 512 + (h * 32 + dg * 8) * 2) = pk;
}

// ---------------- K4: upd = samp @ WoutT + bout -> bf16 ---------------------
// (byte-identical to round 15 — proven)
__global__ __launch_bounds__(256) void k_upd(const unsigned short* __restrict__ A,
                                             const unsigned short* __restrict__ Wt,
                                             const float* __restrict__ bias,
                                             bf16* __restrict__ U) {
  __shared__ unsigned short As[64 * 256];  // 32KB, XOR-swizzled
  const int tid = threadIdx.x;
  const int lane = tid & 63, w = tid >> 6;
  const int row0 = blockIdx.x * 64;
#pragma unroll
  for (int it = 0; it < 8; ++it) {
    const int cid = it * 256 + tid;
    const int row = cid >> 5, c = cid & 31;
    const uint4 q = *(const uint4*)(A + (size_t)(row0 + row) * 256 + c * 8);
    *(uint4*)((char*)As + row * 512 + ((c * 16) ^ ((row & 7) << 4))) = q;
  }
  __syncthreads();
  const int lg16 = lane >> 4, l16 = lane & 15;
  f32x4 acc[4][4] = {};
#pragma unroll
  for (int kk = 0; kk < 8; ++kk) {
    bf16x8 af[4], bh[4];
#pragma unroll
    for (int mf = 0; mf < 4; ++mf) {
      const int row = mf * 16 + l16;
      af[mf] = *(const bf16x8*)((const char*)As + row * 512 +
                                ((kk * 64 + lg16 * 16) ^ ((row & 7) << 4)));
    }
#pragma unroll
    for (int nf = 0; nf < 4; ++nf) {
      const int col = w * 64 + nf * 16 + l16;
      bh[nf] = *(const bf16x8*)(Wt + (size_t)col * 256 + kk * 32 + lg16 * 8);
    }
#pragma unroll
    for (int mf = 0; mf < 4; ++mf)
#pragma unroll
      for (int nf = 0; nf < 4; ++nf)
        acc[mf][nf] = __builtin_amdgcn_mfma_f32_16x16x32_bf16(af[mf], bh[nf], acc[mf][nf], 0, 0, 0);
  }
#pragma unroll
  for (int mf = 0; mf < 4; ++mf) {
    const int rbase = row0 + mf * 16 + lg16 * 4;
#pragma unroll
    for (int nf = 0; nf < 4; ++nf) {
      const int col = w * 64 + nf * 16 + l16;
      const float bb = bias[col];
#pragma unroll
      for (int r = 0; r < 4; ++r)
        U[(size_t)(rbase + r) * 256 + col] = __float2bfloat16(acc[mf][nf][r] + bb);
    }
  }
}

// ---------------- K5: y = LN(qf + upd) — SOLE writer of d_out ---------------
__global__ __launch_bounds__(256) void k_ln(const unsigned short* __restrict__ upd,
                                            const float* __restrict__ qf,
                                            const float* __restrict__ gamma,
                                            const float* __restrict__ beta,
                                            float* __restrict__ y) {
  const int w = threadIdx.x >> 6, lane = threadIdx.x & 63;
  const int row = blockIdx.x * 4 + w;
  const int c = lane * 4;
  const ushort4 u = *(const ushort4*)(upd + (size_t)row * 256 + c);
  const float4 qv = *(const float4*)(qf + (size_t)row * 256 + c);
  const float x0 = qv.x + bf2f(u.x);
  const float x1 = qv.y + bf2f(u.y);
  const float x2 = qv.z + bf2f(u.z);
  const float x3 = qv.w + bf2f(u.w);
  float s1 = x0 + x1 + x2 + x3;
  float s2 = x0 * x0 + x1 * x1 + x2 * x2 + x3 * x3;
#pragma unroll
  for (int o = 32; o >= 1; o >>= 1) {
    s1 += __shfl_xor(s1, o);
    s2 += __shfl_xor(s2, o);
  }
  const float mu = s1 * (1.f / 256.f);
  const float var = s2 * (1.f / 256.f) - mu * mu;
  const float rsig = rsqrtf(var + LN_EPS);
  const float4 g = *(const float4*)(gamma + c);
  const float4 bt = *(const float4*)(beta + c);
  float4 o;
  o.x = (x0 - mu) * rsig * g.x + bt.x;
  o.y = (x1 - mu) * rsig * g.y + bt.y;
  o.z = (x2 - mu) * rsig * g.z + bt.z;
  o.w = (x3 - mu) * rsig * g.w + bt.w;
  *(float4*)(y + (size_t)row * 256 + c) = o;
}

extern "C" void kernel_launch(void* const* d_in, const int* in_sizes, int n_in,
                              void* d_out, int out_size, void* d_ws, size_t ws_size,
                              hipStream_t stream) {
  const float* img_feat = (const float*)d_in[0];
  const unsigned char* img_mask = (const unsigned char*)d_in[2];
  const float* vratio = (const float*)d_in[3];
  const float* qf = (const float*)d_in[4];
  const float* qp = (const float*)d_in[5];
  const float* qpts = (const float*)d_in[6];
  const float* Wv = (const float*)d_in[7];
  const float* bv = (const float*)d_in[8];
  const float* Woff = (const float*)d_in[9];
  const float* boff = (const float*)d_in[10];
  const float* Wattn = (const float*)d_in[11];
  const float* battn = (const float*)d_in[12];
  const float* Wout = (const float*)d_in[13];
  const float* bout = (const float*)d_in[14];
  const float* gamma = (const float*)d_in[15];
  const float* beta = (const float*)d_in[16];

  char* ws = (char*)d_ws;
  bf16* V = (bf16*)ws;                                   // 22.3 MB (head-major; reused as upd)
  bf16* off = (bf16*)(ws + (size_t)NROW * 256 * 2);      // 22.3 MB (reused as samp)
  bf16* lg = (bf16*)(ws + (size_t)NROW * 256 * 4);       // 11.1 MB
  unsigned short* wbase =
      (unsigned short*)(ws + (size_t)NROW * 256 * 4 + (size_t)NROW * 128 * 2);
  unsigned short* WvT = wbase;              // 65536 shorts
  unsigned short* WcatT = WvT + 65536;      // 98304 shorts
  unsigned short* WoutT = WcatT + 98304;    // 65536 shorts -> ends 56.16MB (< proven 56.36MB)

  dim3 blk(256);
  k_trans_all<<<896, blk, 0, stream>>>(Wv, Woff, Wattn, Wout, WvT, WcatT, WoutT);
  k_value<<<NROW / 64, blk, 0, stream>>>(img_feat, WvT, bv, img_mask, V);
  k_offattn<<<NROW / 64, blk, 0, stream>>>(qf, qp, WcatT, boff, battn, off, lg);
  k_sample<<<8 * (NROW / 64), blk, 0, stream>>>(V, off, lg, qpts, vratio,
                                                (unsigned short*)off /* samp alias */);
  k_upd<<<NROW / 64, blk, 0, stream>>>((const unsigned short*)off /* samp */, WoutT,
                                       bout, V /* = upd, dead */);
  k_ln<<<NROW / 4, blk, 0, stream>>>((const unsigned short*)V, qf, gamma, beta,
                                     (float*)d_out);
}